// Round 7
// baseline (237.589 us; speedup 1.0000x reference)
//
#include <hip/hip_runtime.h>
#include <math.h>

#define B_   16
#define I_   2048
#define AIN_ 16
#define O_   64
#define J_   2048     // O*A_OUT
#define JP_  1024     // j as float2 columns

// votes kernel geometry: 256-thread blocks (-> >64 VGPR budget, unlike the
// 1024-thread blocks of rounds 1-6 which the backend pins to 64 VGPRs)
#define V_IPB  16     // i's per votes block
#define V_NIS  128    // i-slabs
#define V_GRID (V_NIS * 4)   // x4 j-tiles of 512 columns

// route kernel geometry: 1024-thread blocks, grid 512 = 256 i-slabs x 2
// b-halves -> 2 blocks/CU so softmax barriers of one block hide under the
// other block's votes loads (rounds 4-6 ran 1 block/CU).
#define R_IPB  8
#define R_NIS  256

// bf16 pack/unpack (RNE). Inputs finite -> no NaN handling needed.
__device__ __forceinline__ unsigned bf16rne(float f) {
  unsigned u = __float_as_uint(f);
  return (u + 0x7FFFu + ((u >> 16) & 1u)) >> 16;
}
__device__ __forceinline__ float bf16lo(unsigned p) { return __uint_as_float(p << 16); }
__device__ __forceinline__ float bf16hi(unsigned p) { return __uint_as_float(p & 0xFFFF0000u); }

// non-temporal float2 load (W is a read-once 268 MB stream; keep it out of
// L3 so the 134 MB votes working set stays resident for the route passes)
__device__ __forceinline__ float2 ntload2(const float2* p) {
  union { double d; float2 f; } u;
  u.d = __builtin_nontemporal_load((const double*)p);
  return u.f;
}

// -------------------------------------------------------------------------
// votes_p0_kernel: votes[i,b,j] (packed bf16x2) AND the pass-0 partial
// preact (uniform route = 1/64) -> part0[slab][b][512 j].
// 256 threads, 2 j/thread, block covers 16 i x 512 j. W read EXACTLY once
// (nt). Live regs ~85 (v[16]f2 + acc[16]f2 + w + addr) — fine at 256-thread
// block sizes where the compiler can allocate >64 VGPRs.
// -------------------------------------------------------------------------
__global__ __launch_bounds__(256) void votes_p0_kernel(
    const float* __restrict__ x, const float* __restrict__ W,
    unsigned* __restrict__ votes, float* __restrict__ part0)
{
  __shared__ float x_lds[V_IPB * B_ * AIN_];   // 16 KB, [il][b][a]
  const int tid = threadIdx.x;
  const int islab = blockIdx.x >> 2, jt = blockIdx.x & 3;
  const int i0 = islab * V_IPB;

  for (int e = tid; e < V_IPB * B_ * AIN_; e += 256) {
    int il = e >> 8, b = (e >> 4) & 15, a = e & 15;
    x_lds[il * 256 + b * 16 + a] =
        x[(size_t)b * (I_ * AIN_) + (size_t)(i0 + il) * AIN_ + a];
  }
  __syncthreads();

  const float2* __restrict__ Wq = (const float2*)W;
  const int jp = jt * 256 + tid;               // float2 column 0..1023

  float2 acc[16];
  #pragma unroll
  for (int b = 0; b < 16; ++b) acc[b] = make_float2(0.f, 0.f);

  for (int il = 0; il < V_IPB; ++il) {
    const int i = i0 + il;
    const float2* __restrict__ Wi = Wq + (size_t)i * (AIN_ * JP_) + jp;
    const float2* __restrict__ xq = (const float2*)x_lds + il * 128; // [b][a2]

    float2 v[16];
    #pragma unroll
    for (int b = 0; b < 16; ++b) v[b] = make_float2(0.f, 0.f);

    #pragma unroll
    for (int a2 = 0; a2 < 8; ++a2) {
      float2 w0 = ntload2(Wi + (size_t)(2 * a2 + 0) * JP_);
      float2 w1 = ntload2(Wi + (size_t)(2 * a2 + 1) * JP_);
      #pragma unroll
      for (int b = 0; b < 16; ++b) {
        float2 xv = xq[b * 8 + a2];            // LDS broadcast
        v[b].x = fmaf(xv.x, w0.x, v[b].x);
        v[b].y = fmaf(xv.x, w0.y, v[b].y);
        v[b].x = fmaf(xv.y, w1.x, v[b].x);
        v[b].y = fmaf(xv.y, w1.y, v[b].y);
      }
    }

    unsigned* __restrict__ vo = votes + (size_t)i * (B_ * JP_) + jp;
    #pragma unroll
    for (int b = 0; b < 16; ++b) {
      vo[(size_t)b * JP_] = bf16rne(v[b].x) | (bf16rne(v[b].y) << 16);
      acc[b].x += v[b].x;  acc[b].y += v[b].y;
    }
  }

  // part0 layout [512 slab = islab*4 + jt][16 b][256 f2]
  float2* __restrict__ po =
      (float2*)part0 + (size_t)blockIdx.x * (B_ * 256) + tid;
  #pragma unroll
  for (int b = 0; b < 16; ++b)
    po[(size_t)b * 256] = make_float2(acc[b].x * (1.0f / 64.0f),
                                      acc[b].y * (1.0f / 64.0f));
}

// -------------------------------------------------------------------------
// reduce_squash0: act0 = squash( sum over 128 i-slabs of part0 + bias ).
// part0 float layout: [islab*4 + jt][16 b][512 j]. One wave per (b,o);
// lane halves q split the 128 slabs.
// -------------------------------------------------------------------------
__global__ __launch_bounds__(256) void reduce_squash0(
    const float* __restrict__ part0, const float* __restrict__ bias,
    float* __restrict__ act)
{
  const int wave = (blockIdx.x * 256 + threadIdx.x) >> 6;   // b*64 + o
  const int L = threadIdx.x & 63;
  const int a = L & 31, q = L >> 5;
  const int b = wave >> 6, o = wave & 63;
  const int j = o * 32 + a;
  const int jt = j >> 9, jloc = j & 511;
  const float* __restrict__ base =
      part0 + (size_t)jt * (B_ * 512) + (size_t)b * 512 + jloc;

  float s0 = 0.f, s1 = 0.f;
  #pragma unroll 4
  for (int k = 0; k < 64; k += 2) {
    s0 += base[(size_t)(q * 64 + k)     * (4 * B_ * 512)];
    s1 += base[(size_t)(q * 64 + k + 1) * (4 * B_ * 512)];
  }
  float s = s0 + s1;
  s += __shfl_xor(s, 32);

  float p = s + bias[j];
  float ns = p * p;                            // squash over 32-lane a-group
  ns += __shfl_xor(ns, 1);  ns += __shfl_xor(ns, 2);
  ns += __shfl_xor(ns, 4);  ns += __shfl_xor(ns, 8);
  ns += __shfl_xor(ns, 16);
  if (L < 32) act[(size_t)b * J_ + j] = p * sqrtf(ns) / (1.0f + ns);
}

// -------------------------------------------------------------------------
// route_kernel<PASS> (PASS = 1,2): one routing iteration over bf16 votes.
// Block = one 8-b half x one 8-i slab x all 2048 j (1024 thr, 2 j/thread).
//   PASS 1: dist = votes.act0; logits := dist; route = softmax(dist)
//   PASS 2: dist = votes.act1; route = softmax(logits + dist)
// Live state ~45 regs (acc f2[8] + av f2[8] + vp[8]) -> fits the 64-VGPR
// budget of 1024-thread blocks; 2 blocks/CU.
// -------------------------------------------------------------------------
template<int PASS>
__global__ __launch_bounds__(1024) void route_kernel(
    const unsigned* __restrict__ votes, const float* __restrict__ act_in,
    float* __restrict__ part, float* __restrict__ logits)
{
  __shared__ float d_lds[8 * O_];              // 2 KB, distances
  __shared__ float r_lds[8 * O_];              // 2 KB, route

  const int tid = threadIdx.x;
  const int islab = blockIdx.x >> 1, bh = blockIdx.x & 1;
  const int i0 = islab * R_IPB;
  const int og = tid >> 4;       // o of this thread's two columns (0..63)
  const int lg = tid & 15;       // lane within the 16-lane o-group
  const float2* __restrict__ actq = (const float2*)act_in;

  float2 acc[8];
  #pragma unroll
  for (int bb = 0; bb < 8; ++bb) acc[bb] = make_float2(0.f, 0.f);

  float2 av[8];
  #pragma unroll
  for (int bb = 0; bb < 8; ++bb)
    av[bb] = actq[(size_t)(bh * 8 + bb) * JP_ + tid];

  for (int il = 0; il < R_IPB; ++il) {
    const int i = i0 + il;
    const unsigned* __restrict__ vo =
        votes + (size_t)i * (B_ * JP_) + (size_t)(bh * 8) * JP_ + tid;
    unsigned vp[8];
    #pragma unroll
    for (int bb = 0; bb < 8; ++bb) vp[bb] = vo[(size_t)bb * JP_];

    // distances[b][o] = sum_a v*act: in-thread pair + 4-step xor over 16
    #pragma unroll
    for (int bb = 0; bb < 8; ++bb) {
      float c = bf16lo(vp[bb]) * av[bb].x + bf16hi(vp[bb]) * av[bb].y;
      c += __shfl_xor(c, 1);  c += __shfl_xor(c, 2);
      c += __shfl_xor(c, 4);  c += __shfl_xor(c, 8);
      if (lg == bb) d_lds[bb * 64 + og] = c;
    }
    __syncthreads();

    // softmax over o (waves 0..7: one wave per bb; lane = o)
    if (tid < 512) {
      const int bb2 = tid >> 6, o2 = tid & 63;
      const int b2  = bh * 8 + bb2;
      float ell = d_lds[tid];
      if (PASS == 2) ell += logits[((size_t)b2 * I_ + i) * O_ + o2];
      if (PASS == 1) logits[((size_t)b2 * I_ + i) * O_ + o2] = ell;
      float m = ell;
      m = fmaxf(m, __shfl_xor(m, 32)); m = fmaxf(m, __shfl_xor(m, 16));
      m = fmaxf(m, __shfl_xor(m, 8));  m = fmaxf(m, __shfl_xor(m, 4));
      m = fmaxf(m, __shfl_xor(m, 2));  m = fmaxf(m, __shfl_xor(m, 1));
      float e = __expf(ell - m);
      float s = e;
      s += __shfl_xor(s, 32); s += __shfl_xor(s, 16); s += __shfl_xor(s, 8);
      s += __shfl_xor(s, 4);  s += __shfl_xor(s, 2);  s += __shfl_xor(s, 1);
      r_lds[tid] = e / s;
    }
    __syncthreads();

    #pragma unroll
    for (int bb = 0; bb < 8; ++bb) {
      float r = r_lds[bb * 64 + og];
      acc[bb].x = fmaf(r, bf16lo(vp[bb]), acc[bb].x);
      acc[bb].y = fmaf(r, bf16hi(vp[bb]), acc[bb].y);
    }
  }

  // part float layout: [islab][bh][bb][2048 j]
  float2* __restrict__ po =
      (float2*)part + (size_t)blockIdx.x * (8 * JP_) + tid;
  #pragma unroll
  for (int bb = 0; bb < 8; ++bb)
    po[(size_t)bb * JP_] = acc[bb];
}

// -------------------------------------------------------------------------
// reduce_squash: preact[b][j] = sum over 256 i-slabs of part; p += bias;
// squash over a. part float layout [islab][2 bh][8 bb][2048 j].
// One wave per (b,o); lane halves q split the 256 slab-partials.
// -------------------------------------------------------------------------
__global__ __launch_bounds__(256) void reduce_squash(
    const float* __restrict__ part, const float* __restrict__ bias,
    float* __restrict__ out)
{
  const int wave = (blockIdx.x * 256 + threadIdx.x) >> 6;   // b*64 + o
  const int L = threadIdx.x & 63;
  const int a = L & 31, q = L >> 5;
  const int b = wave >> 6, o = wave & 63;
  const int j = o * 32 + a;
  const float* __restrict__ base =
      part + (size_t)(b >> 3) * (8 * J_) + (size_t)(b & 7) * J_ + j;

  float s0 = 0.f, s1 = 0.f;
  #pragma unroll 4
  for (int k = 0; k < 128; k += 2) {
    s0 += base[(size_t)(q * 128 + k)     * (B_ * J_)];
    s1 += base[(size_t)(q * 128 + k + 1) * (B_ * J_)];
  }
  float s = s0 + s1;
  s += __shfl_xor(s, 32);              // combine the two 128-slab halves

  float p = s + bias[j];
  float ns = p * p;
  ns += __shfl_xor(ns, 1);  ns += __shfl_xor(ns, 2);
  ns += __shfl_xor(ns, 4);  ns += __shfl_xor(ns, 8);
  ns += __shfl_xor(ns, 16);
  if (L < 32) out[(size_t)b * J_ + j] = p * sqrtf(ns) / (1.0f + ns);
}

// -------------------------------------------------------------------------
// FALLBACK (ws too small): W-streaming pass kernel, writing part in the
// route layout [islab][bh][bb][2048] so the same reduce_squash applies.
// -------------------------------------------------------------------------
template<int PASS>
__global__ __launch_bounds__(1024) void fb_pass_kernel(
    const float* __restrict__ x, const float* __restrict__ W,
    const float* __restrict__ act_in, float* __restrict__ part,
    float* __restrict__ logits)
{
  __shared__ float x_lds[8 * B_ * AIN_];
  __shared__ float d_lds[8 * O_];
  __shared__ float r_lds[8 * O_];
  const int tid = threadIdx.x, blk = blockIdx.x, i0 = blk * 8;
  for (int e = tid; e < 8 * B_ * AIN_; e += 1024) {
    int b = e >> 7, il = (e >> 4) & 7, a = e & 15;
    x_lds[il * 256 + b * 16 + a] =
        x[(size_t)b * (I_ * AIN_) + (size_t)(i0 + il) * AIN_ + a];
  }
  __syncthreads();
  const int og = tid >> 4, lg = tid & 15;
  float2 acc[16];
  #pragma unroll
  for (int b = 0; b < 16; ++b) acc[b] = make_float2(0.f, 0.f);
  const float2* __restrict__ Wq   = (const float2*)W;
  const float2* __restrict__ actq = (const float2*)act_in;
  for (int il = 0; il < 8; ++il) {
    const int i = i0 + il;
    const float2* __restrict__ Wi = Wq + (size_t)i * (AIN_ * JP_);
    const float4* __restrict__ xq = (const float4*)x_lds + il * 64;
    for (int h = 0; h < 2; ++h) {
      float2 v[8];
      #pragma unroll
      for (int bb = 0; bb < 8; ++bb) v[bb] = make_float2(0.f, 0.f);
      #pragma unroll
      for (int a4 = 0; a4 < 4; ++a4) {
        float2 w0 = Wi[(size_t)(a4 * 4 + 0) * JP_ + tid];
        float2 w1 = Wi[(size_t)(a4 * 4 + 1) * JP_ + tid];
        float2 w2 = Wi[(size_t)(a4 * 4 + 2) * JP_ + tid];
        float2 w3 = Wi[(size_t)(a4 * 4 + 3) * JP_ + tid];
        #pragma unroll
        for (int bb = 0; bb < 8; ++bb) {
          float4 xv = xq[(h * 8 + bb) * 4 + a4];
          v[bb].x = fmaf(xv.x, w0.x, v[bb].x); v[bb].y = fmaf(xv.x, w0.y, v[bb].y);
          v[bb].x = fmaf(xv.y, w1.x, v[bb].x); v[bb].y = fmaf(xv.y, w1.y, v[bb].y);
          v[bb].x = fmaf(xv.z, w2.x, v[bb].x); v[bb].y = fmaf(xv.z, w2.y, v[bb].y);
          v[bb].x = fmaf(xv.w, w3.x, v[bb].x); v[bb].y = fmaf(xv.w, w3.y, v[bb].y);
        }
      }
      if (PASS == 0) {
        #pragma unroll
        for (int bb = 0; bb < 8; ++bb) {
          acc[h * 8 + bb].x += v[bb].x; acc[h * 8 + bb].y += v[bb].y;
        }
      } else {
        #pragma unroll
        for (int bb = 0; bb < 8; ++bb) {
          const int b = h * 8 + bb;
          float2 avv = actq[(size_t)b * JP_ + tid];
          float c = v[bb].x * avv.x + v[bb].y * avv.y;
          c += __shfl_xor(c, 1); c += __shfl_xor(c, 2);
          c += __shfl_xor(c, 4); c += __shfl_xor(c, 8);
          if (lg == bb) d_lds[bb * 64 + og] = c;
        }
        __syncthreads();
        if (tid < 512) {
          const int bb2 = tid >> 6, o2 = tid & 63;
          const int b2  = h * 8 + bb2;
          float ell = d_lds[tid];
          if (PASS == 2) ell += logits[((size_t)b2 * I_ + i) * O_ + o2];
          if (PASS == 1) logits[((size_t)b2 * I_ + i) * O_ + o2] = ell;
          float m = ell;
          m = fmaxf(m, __shfl_xor(m, 32)); m = fmaxf(m, __shfl_xor(m, 16));
          m = fmaxf(m, __shfl_xor(m, 8));  m = fmaxf(m, __shfl_xor(m, 4));
          m = fmaxf(m, __shfl_xor(m, 2));  m = fmaxf(m, __shfl_xor(m, 1));
          float e = __expf(ell - m);
          float s = e;
          s += __shfl_xor(s, 32); s += __shfl_xor(s, 16); s += __shfl_xor(s, 8);
          s += __shfl_xor(s, 4);  s += __shfl_xor(s, 2);  s += __shfl_xor(s, 1);
          r_lds[tid] = e / s;
        }
        __syncthreads();
        #pragma unroll
        for (int bb = 0; bb < 8; ++bb) {
          float r = r_lds[bb * 64 + og];
          acc[h * 8 + bb].x = fmaf(r, v[bb].x, acc[h * 8 + bb].x);
          acc[h * 8 + bb].y = fmaf(r, v[bb].y, acc[h * 8 + bb].y);
        }
      }
    }
  }
  const float sc = (PASS == 0) ? (1.0f / 64.0f) : 1.0f;
  #pragma unroll
  for (int b = 0; b < 16; ++b) {
    float2* __restrict__ po = (float2*)part +
        ((size_t)(blk * 2 + (b >> 3)) * 8 + (b & 7)) * JP_ + tid;
    *po = make_float2(acc[b].x * sc, acc[b].y * sc);
  }
}

// -------------------------------------------------------------------------
extern "C" void kernel_launch(void* const* d_in, const int* in_sizes, int n_in,
                              void* d_out, int out_size, void* d_ws, size_t ws_size,
                              hipStream_t stream) {
  const float* x    = (const float*)d_in[0];
  const float* W    = (const float*)d_in[1];
  const float* bias = (const float*)d_in[2];
  float* out = (float*)d_out;

  float*    part   = (float*)d_ws;                        // 32 MB (part0 aliases first 16 MB)
  float*    act    = part + (size_t)256 * (B_ * J_);      // 128 KB
  float*    logits = act + (B_ * J_);                     // 8 MB
  unsigned* votes  = (unsigned*)(logits + (size_t)B_ * I_ * O_);  // 134 MB
  const size_t need = ((size_t)256 * B_ * J_ + B_ * J_ + (size_t)B_ * I_ * O_) * 4
                    + (size_t)I_ * B_ * JP_ * 4;

  if (ws_size >= need) {
    votes_p0_kernel<<<V_GRID, 256, 0, stream>>>(x, W, votes, part);
    reduce_squash0<<<256, 256, 0, stream>>>(part, bias, act);
    route_kernel<1><<<R_NIS * 2, 1024, 0, stream>>>(votes, act, part, logits);
    reduce_squash<<<256, 256, 0, stream>>>(part, bias, act);
    route_kernel<2><<<R_NIS * 2, 1024, 0, stream>>>(votes, act, part, logits);
    reduce_squash<<<256, 256, 0, stream>>>(part, bias, out);
  } else {
    fb_pass_kernel<0><<<256, 1024, 0, stream>>>(x, W, act, part, logits);
    reduce_squash<<<256, 256, 0, stream>>>(part, bias, act);
    fb_pass_kernel<1><<<256, 1024, 0, stream>>>(x, W, act, part, logits);
    reduce_squash<<<256, 256, 0, stream>>>(part, bias, act);
    fb_pass_kernel<2><<<256, 1024, 0, stream>>>(x, W, act, part, logits);
    reduce_squash<<<256, 256, 0, stream>>>(part, bias, out);
  }
}

// Round 8
// 198.976 us; speedup vs baseline: 1.1941x; 1.1941x over previous
//
#include <hip/hip_runtime.h>
#include <math.h>

#define B_   16
#define I_   2048
#define AIN_ 16
#define O_   64
#define J_   2048     // O*A_OUT
#define JP_  1024     // j as packed bf16x2 / float2 columns

// bf16 pack/unpack (RNE). Inputs finite -> no NaN handling needed.
__device__ __forceinline__ unsigned bf16rne(float f) {
  unsigned u = __float_as_uint(f);
  return (u + 0x7FFFu + ((u >> 16) & 1u)) >> 16;
}
__device__ __forceinline__ float bf16lo(unsigned p) { return __uint_as_float(p << 16); }
__device__ __forceinline__ float bf16hi(unsigned p) { return __uint_as_float(p & 0xFFFF0000u); }

// non-temporal float2 load (W is a read-once 268 MB stream; keep it out of
// L3 so the 134 MB votes working set stays resident for the route passes)
__device__ __forceinline__ float2 ntload2(const float2* p) {
  union { double d; float2 f; } u;
  u.d = __builtin_nontemporal_load((const double*)p);
  return u.f;
}

// -------------------------------------------------------------------------
// votes_kernel: votes[i,b,jp] = packed bf16x2 of sum_a x[b,i,a]*W[i,a,j].
// 512-thread blocks, grid 512 (= 256 i-slabs x 2 j-halves) -> 4 blocks/CU,
// 32 waves/CU (rounds 4-7 ran 16): double the latency-hiding for the pure
// HBM stream. 2 j/thread; live regs ~46 (v[16]f2 + w f2x2 + addr), safely
// under the 64-VGPR budget 512/1024-thread blocks get pinned to.
// W read EXACTLY once (nt).
// -------------------------------------------------------------------------
__global__ __launch_bounds__(512) void votes_kernel(
    const float* __restrict__ x, const float* __restrict__ W,
    unsigned* __restrict__ votes)
{
  __shared__ float x_lds[8 * B_ * AIN_];       // 8 KB, [il][b][a]
  const int tid = threadIdx.x;
  const int islab = blockIdx.x >> 1, jt = blockIdx.x & 1;
  const int i0 = islab * 8;

  for (int e = tid; e < 8 * B_ * AIN_; e += 512) {
    int b = e >> 7, il = (e >> 4) & 7, a = e & 15;
    x_lds[il * 256 + b * 16 + a] =
        x[(size_t)b * (I_ * AIN_) + (size_t)(i0 + il) * AIN_ + a];
  }
  __syncthreads();

  const float2* __restrict__ Wq = (const float2*)W;
  const int jp = jt * 512 + tid;               // float2 column 0..1023

  for (int il = 0; il < 8; ++il) {
    const int i = i0 + il;
    const float2* __restrict__ Wi = Wq + (size_t)i * (AIN_ * JP_) + jp;
    const float2* __restrict__ xq = (const float2*)x_lds + il * 128; // [b][a2]

    float2 v[16];
    #pragma unroll
    for (int b = 0; b < 16; ++b) v[b] = make_float2(0.f, 0.f);

    #pragma unroll
    for (int a2 = 0; a2 < 8; ++a2) {
      float2 w0 = ntload2(Wi + (size_t)(2 * a2 + 0) * JP_);
      float2 w1 = ntload2(Wi + (size_t)(2 * a2 + 1) * JP_);
      #pragma unroll
      for (int b = 0; b < 16; ++b) {
        float2 xv = xq[b * 8 + a2];            // LDS broadcast
        v[b].x = fmaf(xv.x, w0.x, v[b].x);
        v[b].y = fmaf(xv.x, w0.y, v[b].y);
        v[b].x = fmaf(xv.y, w1.x, v[b].x);
        v[b].y = fmaf(xv.y, w1.y, v[b].y);
      }
    }

    unsigned* __restrict__ vo = votes + (size_t)i * (B_ * JP_) + jp;
    #pragma unroll
    for (int b = 0; b < 16; ++b)
      vo[(size_t)b * JP_] = bf16rne(v[b].x) | (bf16rne(v[b].y) << 16);
  }
}

// -------------------------------------------------------------------------
// reduce0_kernel: act0[b,j] = squash( (1/64)*sum_i votes[i,b,j] + bias ).
// Reads votes straight out of L3 (just written). Packed uint loads
// (2 j/thread, 256 B/wave-instr — 2x round 6's scalar ushort reads).
// Grid 256 = b(16) x 16 jp-tiles(64 jp); block 256 = 64 jp x 4 i-subsets.
// -------------------------------------------------------------------------
__global__ __launch_bounds__(256) void reduce0_kernel(
    const unsigned* __restrict__ votes, const float* __restrict__ bias,
    float* __restrict__ act)
{
  __shared__ float2 red[4][64];
  const int b = blockIdx.x >> 4, jt = blockIdx.x & 15;
  const int jl = threadIdx.x & 63, is = threadIdx.x >> 6;
  const int jp = jt * 64 + jl;                 // packed column 0..1023
  const unsigned* __restrict__ vp = votes + (size_t)b * JP_ + jp;

  float2 s0 = make_float2(0.f, 0.f), s1 = make_float2(0.f, 0.f);
  #pragma unroll 4
  for (int k = 0; k < 512; k += 2) {
    unsigned u0 = vp[(size_t)(is + 4 * k)     * (B_ * JP_)];
    unsigned u1 = vp[(size_t)(is + 4 * k + 4) * (B_ * JP_)];
    s0.x += bf16lo(u0); s0.y += bf16hi(u0);
    s1.x += bf16lo(u1); s1.y += bf16hi(u1);
  }
  red[is][jl] = make_float2(s0.x + s1.x, s0.y + s1.y);
  __syncthreads();

  if (threadIdx.x < 64) {
    float2 r0 = red[0][jl], r1 = red[1][jl], r2 = red[2][jl], r3 = red[3][jl];
    const float2 bq = ((const float2*)bias)[jp];
    float px = (r0.x + r1.x + r2.x + r3.x) * (1.0f / 64.0f) + bq.x;
    float py = (r0.y + r1.y + r2.y + r3.y) * (1.0f / 64.0f) + bq.y;
    float ns = px * px + py * py;              // squash over o-group: 16 lanes
    ns += __shfl_xor(ns, 1);  ns += __shfl_xor(ns, 2);
    ns += __shfl_xor(ns, 4);  ns += __shfl_xor(ns, 8);
    float sc = sqrtf(ns) / (1.0f + ns);
    ((float2*)act)[(size_t)b * JP_ + jp] = make_float2(px * sc, py * sc);
  }
}

// -------------------------------------------------------------------------
// route_kernel<PASS> (PASS = 1,2): one routing iteration over bf16 votes.
// Block = 4 b x 8 i x all 2048 j; 512 threads, 4 j/thread (uint2 loads,
// 8 B/lane); grid 1024 (= 256 i-slabs x 4 b-quads) -> 4 blocks/CU so one
// block's softmax barriers hide under 3 other blocks' loads (rounds 4-7: 2).
//   PASS 1: dist = votes.act0; logits := dist; route = softmax(dist)
//   PASS 2: dist = votes.act1; route = softmax(logits + dist)
// Live regs ~50 (acc f4[4] + av f4[4] + vp u2[4] + temps) < 64 budget.
// part float layout: [islab*4+bq][4 bb][2048 j] == part + islab*32768 +
// b*2048 + j — bit-identical to rounds 4-7, so reduce_squash is unchanged.
// -------------------------------------------------------------------------
template<int PASS>
__global__ __launch_bounds__(512) void route_kernel(
    const uint2* __restrict__ votes2, const float* __restrict__ act_in,
    float* __restrict__ part, float* __restrict__ logits)
{
  __shared__ float d_lds[4 * O_];              // 1 KB, distances
  __shared__ float r_lds[4 * O_];              // 1 KB, route

  const int jq = threadIdx.x;                  // uint2 column 0..511 (j = 4*jq)
  const int islab = blockIdx.x >> 2, bq = blockIdx.x & 3;
  const int i0 = islab * 8;
  const int o = jq >> 3;                       // this thread's o (0..63)
  const int l8 = jq & 7;                       // lane within 8-thread o-group
  const float4* __restrict__ actq = (const float4*)act_in;

  float4 av[4];
  #pragma unroll
  for (int bb = 0; bb < 4; ++bb)
    av[bb] = actq[(size_t)(bq * 4 + bb) * 512 + jq];

  float4 acc[4];
  #pragma unroll
  for (int bb = 0; bb < 4; ++bb) acc[bb] = make_float4(0.f, 0.f, 0.f, 0.f);

  for (int il = 0; il < 8; ++il) {
    const int i = i0 + il;
    const uint2* __restrict__ vo =
        votes2 + (size_t)i * (B_ * 512) + (size_t)(bq * 4) * 512 + jq;
    uint2 vp[4];
    #pragma unroll
    for (int bb = 0; bb < 4; ++bb) vp[bb] = vo[(size_t)bb * 512];

    // distances[b][o] = sum_a v*act: in-thread 4 + 3-step xor over 8 lanes
    #pragma unroll
    for (int bb = 0; bb < 4; ++bb) {
      float c = bf16lo(vp[bb].x) * av[bb].x + bf16hi(vp[bb].x) * av[bb].y
              + bf16lo(vp[bb].y) * av[bb].z + bf16hi(vp[bb].y) * av[bb].w;
      c += __shfl_xor(c, 1);  c += __shfl_xor(c, 2);  c += __shfl_xor(c, 4);
      if (l8 == bb) d_lds[bb * 64 + o] = c;
    }
    __syncthreads();

    // softmax over o (waves 0..3: one wave per bb; lane = o)
    if (threadIdx.x < 256) {
      const int bb2 = threadIdx.x >> 6, o2 = threadIdx.x & 63;
      const int b2  = bq * 4 + bb2;
      float ell = d_lds[threadIdx.x];
      if (PASS == 2) ell += logits[((size_t)b2 * I_ + i) * O_ + o2];
      if (PASS == 1) logits[((size_t)b2 * I_ + i) * O_ + o2] = ell;
      float m = ell;
      m = fmaxf(m, __shfl_xor(m, 32)); m = fmaxf(m, __shfl_xor(m, 16));
      m = fmaxf(m, __shfl_xor(m, 8));  m = fmaxf(m, __shfl_xor(m, 4));
      m = fmaxf(m, __shfl_xor(m, 2));  m = fmaxf(m, __shfl_xor(m, 1));
      float e = __expf(ell - m);
      float s = e;
      s += __shfl_xor(s, 32); s += __shfl_xor(s, 16); s += __shfl_xor(s, 8);
      s += __shfl_xor(s, 4);  s += __shfl_xor(s, 2);  s += __shfl_xor(s, 1);
      r_lds[threadIdx.x] = e / s;
    }
    __syncthreads();

    #pragma unroll
    for (int bb = 0; bb < 4; ++bb) {
      float r = r_lds[bb * 64 + o];
      acc[bb].x = fmaf(r, bf16lo(vp[bb].x), acc[bb].x);
      acc[bb].y = fmaf(r, bf16hi(vp[bb].x), acc[bb].y);
      acc[bb].z = fmaf(r, bf16lo(vp[bb].y), acc[bb].z);
      acc[bb].w = fmaf(r, bf16hi(vp[bb].y), acc[bb].w);
    }
  }

  // part: [slab = blockIdx.x][4 bb][512 float4]
  float4* __restrict__ po =
      (float4*)part + (size_t)blockIdx.x * (4 * 512) + jq;
  #pragma unroll
  for (int bb = 0; bb < 4; ++bb)
    po[(size_t)bb * 512] = acc[bb];
}

// -------------------------------------------------------------------------
// reduce_squash: preact[b][j] = sum over 256 i-slabs of part; p += bias;
// squash over a. part float layout: islab*32768 + b*2048 + j.
// One wave per (b,o); lane halves q split the 256 slab-partials.
// -------------------------------------------------------------------------
__global__ __launch_bounds__(256) void reduce_squash(
    const float* __restrict__ part, const float* __restrict__ bias,
    float* __restrict__ out)
{
  const int wave = (blockIdx.x * 256 + threadIdx.x) >> 6;   // b*64 + o
  const int L = threadIdx.x & 63;
  const int a = L & 31, q = L >> 5;
  const int b = wave >> 6, o = wave & 63;
  const int j = o * 32 + a;
  const float* __restrict__ base = part + (size_t)b * J_ + j;

  float s0 = 0.f, s1 = 0.f;
  #pragma unroll 4
  for (int k = 0; k < 128; k += 2) {
    s0 += base[(size_t)(q * 128 + k)     * (B_ * J_)];
    s1 += base[(size_t)(q * 128 + k + 1) * (B_ * J_)];
  }
  float s = s0 + s1;
  s += __shfl_xor(s, 32);              // combine the two 128-slab halves

  float p = s + bias[j];
  float ns = p * p;
  ns += __shfl_xor(ns, 1);  ns += __shfl_xor(ns, 2);
  ns += __shfl_xor(ns, 4);  ns += __shfl_xor(ns, 8);
  ns += __shfl_xor(ns, 16);
  if (L < 32) out[(size_t)b * J_ + j] = p * sqrtf(ns) / (1.0f + ns);
}

// -------------------------------------------------------------------------
// FALLBACK (ws too small): W-streaming pass kernel, part at b*2048+j per
// islab (same arithmetic as reduce_squash expects).
// -------------------------------------------------------------------------
template<int PASS>
__global__ __launch_bounds__(1024) void fb_pass_kernel(
    const float* __restrict__ x, const float* __restrict__ W,
    const float* __restrict__ act_in, float* __restrict__ part,
    float* __restrict__ logits)
{
  __shared__ float x_lds[8 * B_ * AIN_];
  __shared__ float d_lds[8 * O_];
  __shared__ float r_lds[8 * O_];
  const int tid = threadIdx.x, blk = blockIdx.x, i0 = blk * 8;
  for (int e = tid; e < 8 * B_ * AIN_; e += 1024) {
    int b = e >> 7, il = (e >> 4) & 7, a = e & 15;
    x_lds[il * 256 + b * 16 + a] =
        x[(size_t)b * (I_ * AIN_) + (size_t)(i0 + il) * AIN_ + a];
  }
  __syncthreads();
  const int og = tid >> 4, lg = tid & 15;
  float2 acc[16];
  #pragma unroll
  for (int b = 0; b < 16; ++b) acc[b] = make_float2(0.f, 0.f);
  const float2* __restrict__ Wq   = (const float2*)W;
  const float2* __restrict__ actq = (const float2*)act_in;
  for (int il = 0; il < 8; ++il) {
    const int i = i0 + il;
    const float2* __restrict__ Wi = Wq + (size_t)i * (AIN_ * JP_);
    const float4* __restrict__ xq = (const float4*)x_lds + il * 64;
    for (int h = 0; h < 2; ++h) {
      float2 v[8];
      #pragma unroll
      for (int bb = 0; bb < 8; ++bb) v[bb] = make_float2(0.f, 0.f);
      #pragma unroll
      for (int a4 = 0; a4 < 4; ++a4) {
        float2 w0 = Wi[(size_t)(a4 * 4 + 0) * JP_ + tid];
        float2 w1 = Wi[(size_t)(a4 * 4 + 1) * JP_ + tid];
        float2 w2 = Wi[(size_t)(a4 * 4 + 2) * JP_ + tid];
        float2 w3 = Wi[(size_t)(a4 * 4 + 3) * JP_ + tid];
        #pragma unroll
        for (int bb = 0; bb < 8; ++bb) {
          float4 xv = xq[(h * 8 + bb) * 4 + a4];
          v[bb].x = fmaf(xv.x, w0.x, v[bb].x); v[bb].y = fmaf(xv.x, w0.y, v[bb].y);
          v[bb].x = fmaf(xv.y, w1.x, v[bb].x); v[bb].y = fmaf(xv.y, w1.y, v[bb].y);
          v[bb].x = fmaf(xv.z, w2.x, v[bb].x); v[bb].y = fmaf(xv.z, w2.y, v[bb].y);
          v[bb].x = fmaf(xv.w, w3.x, v[bb].x); v[bb].y = fmaf(xv.w, w3.y, v[bb].y);
        }
      }
      if (PASS == 0) {
        #pragma unroll
        for (int bb = 0; bb < 8; ++bb) {
          acc[h * 8 + bb].x += v[bb].x; acc[h * 8 + bb].y += v[bb].y;
        }
      } else {
        #pragma unroll
        for (int bb = 0; bb < 8; ++bb) {
          const int b = h * 8 + bb;
          float2 avv = actq[(size_t)b * JP_ + tid];
          float c = v[bb].x * avv.x + v[bb].y * avv.y;
          c += __shfl_xor(c, 1); c += __shfl_xor(c, 2);
          c += __shfl_xor(c, 4); c += __shfl_xor(c, 8);
          if (lg == bb) d_lds[bb * 64 + og] = c;
        }
        __syncthreads();
        if (tid < 512) {
          const int bb2 = tid >> 6, o2 = tid & 63;
          const int b2  = h * 8 + bb2;
          float ell = d_lds[tid];
          if (PASS == 2) ell += logits[((size_t)b2 * I_ + i) * O_ + o2];
          if (PASS == 1) logits[((size_t)b2 * I_ + i) * O_ + o2] = ell;
          float m = ell;
          m = fmaxf(m, __shfl_xor(m, 32)); m = fmaxf(m, __shfl_xor(m, 16));
          m = fmaxf(m, __shfl_xor(m, 8));  m = fmaxf(m, __shfl_xor(m, 4));
          m = fmaxf(m, __shfl_xor(m, 2));  m = fmaxf(m, __shfl_xor(m, 1));
          float e = __expf(ell - m);
          float s = e;
          s += __shfl_xor(s, 32); s += __shfl_xor(s, 16); s += __shfl_xor(s, 8);
          s += __shfl_xor(s, 4);  s += __shfl_xor(s, 2);  s += __shfl_xor(s, 1);
          r_lds[tid] = e / s;
        }
        __syncthreads();
        #pragma unroll
        for (int bb = 0; bb < 8; ++bb) {
          float r = r_lds[bb * 64 + og];
          acc[h * 8 + bb].x = fmaf(r, v[bb].x, acc[h * 8 + bb].x);
          acc[h * 8 + bb].y = fmaf(r, v[bb].y, acc[h * 8 + bb].y);
        }
      }
    }
  }
  const float sc = (PASS == 0) ? (1.0f / 64.0f) : 1.0f;
  #pragma unroll
  for (int b = 0; b < 16; ++b) {
    float2* __restrict__ po = (float2*)part +
        (size_t)blk * (B_ * JP_) + (size_t)b * JP_ + tid;
    *po = make_float2(acc[b].x * sc, acc[b].y * sc);
  }
}

// -------------------------------------------------------------------------
extern "C" void kernel_launch(void* const* d_in, const int* in_sizes, int n_in,
                              void* d_out, int out_size, void* d_ws, size_t ws_size,
                              hipStream_t stream) {
  const float* x    = (const float*)d_in[0];
  const float* W    = (const float*)d_in[1];
  const float* bias = (const float*)d_in[2];
  float* out = (float*)d_out;

  float*    part   = (float*)d_ws;                        // 32 MB
  float*    act    = part + (size_t)256 * (B_ * J_);      // 128 KB
  float*    logits = act + (B_ * J_);                     // 8 MB
  unsigned* votes  = (unsigned*)(logits + (size_t)B_ * I_ * O_);  // 134 MB
  const size_t need = ((size_t)256 * B_ * J_ + B_ * J_ + (size_t)B_ * I_ * O_) * 4
                    + (size_t)I_ * B_ * JP_ * 4;

  if (ws_size >= need) {
    votes_kernel<<<512, 512, 0, stream>>>(x, W, votes);
    reduce0_kernel<<<256, 256, 0, stream>>>(votes, bias, act);
    route_kernel<1><<<1024, 512, 0, stream>>>((const uint2*)votes, act, part, logits);
    reduce_squash<<<256, 256, 0, stream>>>(part, bias, act);
    route_kernel<2><<<1024, 512, 0, stream>>>((const uint2*)votes, act, part, logits);
    reduce_squash<<<256, 256, 0, stream>>>(part, bias, out);
  } else {
    fb_pass_kernel<0><<<256, 1024, 0, stream>>>(x, W, act, part, logits);
    reduce_squash<<<256, 256, 0, stream>>>(part, bias, act);
    fb_pass_kernel<1><<<256, 1024, 0, stream>>>(x, W, act, part, logits);
    reduce_squash<<<256, 256, 0, stream>>>(part, bias, act);
    fb_pass_kernel<2><<<256, 1024, 0, stream>>>(x, W, act, part, logits);
    reduce_squash<<<256, 256, 0, stream>>>(part, bias, out);
  }
}

// Round 9
// 190.460 us; speedup vs baseline: 1.2474x; 1.0447x over previous
//
#include <hip/hip_runtime.h>
#include <math.h>

#define B_   16
#define I_   2048
#define AIN_ 16
#define O_   64
#define J_   2048     // O*A_OUT
#define JP_  1024     // j as packed bf16x2 / float2 columns

// bf16 pack/unpack (RNE). Inputs finite -> no NaN handling needed.
__device__ __forceinline__ unsigned bf16rne(float f) {
  unsigned u = __float_as_uint(f);
  return (u + 0x7FFFu + ((u >> 16) & 1u)) >> 16;
}
__device__ __forceinline__ float bf16lo(unsigned p) { return __uint_as_float(p << 16); }
__device__ __forceinline__ float bf16hi(unsigned p) { return __uint_as_float(p & 0xFFFF0000u); }

// non-temporal float2 load (W is a read-once 268 MB stream; keep it out of
// L3 so the 134 MB votes working set stays resident for the route passes)
__device__ __forceinline__ float2 ntload2(const float2* p) {
  union { double d; float2 f; } u;
  u.d = __builtin_nontemporal_load((const double*)p);
  return u.f;
}

// -------------------------------------------------------------------------
// votes_kernel: votes[i,b,jp] = packed bf16x2 of sum_a x[b,i,a]*W[i,a,j].
// 512-thread blocks, grid 1024 (= 512 i-slabs of 4 i x 2 j-halves) ->
// 4 blocks/CU, 32 waves/CU. 2 j/thread; live regs ~46. W read once (nt).
// -------------------------------------------------------------------------
__global__ __launch_bounds__(512) void votes_kernel(
    const float* __restrict__ x, const float* __restrict__ W,
    unsigned* __restrict__ votes)
{
  __shared__ float x_lds[4 * B_ * AIN_];       // 4 KB, [il][b][a]
  const int tid = threadIdx.x;
  const int islab = blockIdx.x >> 1, jt = blockIdx.x & 1;
  const int i0 = islab * 4;

  for (int e = tid; e < 4 * B_ * AIN_; e += 512) {
    int b = e >> 5 & 15, il = e >> 9, a = e & 15;
    // layout [il][b][a]; recompute indices directly:
    il = e >> 8; b = (e >> 4) & 15; a = e & 15;
    x_lds[il * 256 + b * 16 + a] =
        x[(size_t)b * (I_ * AIN_) + (size_t)(i0 + il) * AIN_ + a];
  }
  __syncthreads();

  const float2* __restrict__ Wq = (const float2*)W;
  const int jp = jt * 512 + tid;               // float2 column 0..1023

  for (int il = 0; il < 4; ++il) {
    const int i = i0 + il;
    const float2* __restrict__ Wi = Wq + (size_t)i * (AIN_ * JP_) + jp;
    const float2* __restrict__ xq = (const float2*)x_lds + il * 128; // [b][a2]

    float2 v[16];
    #pragma unroll
    for (int b = 0; b < 16; ++b) v[b] = make_float2(0.f, 0.f);

    #pragma unroll
    for (int a2 = 0; a2 < 8; ++a2) {
      float2 w0 = ntload2(Wi + (size_t)(2 * a2 + 0) * JP_);
      float2 w1 = ntload2(Wi + (size_t)(2 * a2 + 1) * JP_);
      #pragma unroll
      for (int b = 0; b < 16; ++b) {
        float2 xv = xq[b * 8 + a2];            // LDS broadcast
        v[b].x = fmaf(xv.x, w0.x, v[b].x);
        v[b].y = fmaf(xv.x, w0.y, v[b].y);
        v[b].x = fmaf(xv.y, w1.x, v[b].x);
        v[b].y = fmaf(xv.y, w1.y, v[b].y);
      }
    }

    unsigned* __restrict__ vo = votes + (size_t)i * (B_ * JP_) + jp;
    #pragma unroll
    for (int b = 0; b < 16; ++b)
      vo[(size_t)b * JP_] = bf16rne(v[b].x) | (bf16rne(v[b].y) << 16);
  }
}

// -------------------------------------------------------------------------
// reduce0_kernel v2: act0[b,j] = squash( (1/64)*sum_i votes[i,b,j] + bias ).
// One block per (b,o): grid 1024 (4 blocks/CU, 16 waves/CU — round 8 ran
// this reduction at 4 waves/CU with scalar loads: latency-bound).
// Thread (s=t>>2, q=t&3) loads 32 uint4 (16 B/lane) over i = s + 64k.
// -------------------------------------------------------------------------
__global__ __launch_bounds__(256) void reduce0_kernel(
    const uint4* __restrict__ votes4, const float* __restrict__ bias,
    float* __restrict__ act)
{
  __shared__ float red[64][4][8];              // 8 KB
  const int b = blockIdx.x >> 6, o = blockIdx.x & 63;
  const int t = threadIdx.x, s = t >> 2, q = t & 3;
  const uint4* __restrict__ vp = votes4 + (size_t)b * 256 + (size_t)(o * 4 + q);

  float a0=0.f,a1=0.f,a2=0.f,a3=0.f,a4=0.f,a5=0.f,a6=0.f,a7=0.f;
  #pragma unroll 8
  for (int k = 0; k < 32; ++k) {
    uint4 u = vp[(size_t)(s + 64 * k) * 4096];
    a0 += bf16lo(u.x); a1 += bf16hi(u.x);
    a2 += bf16lo(u.y); a3 += bf16hi(u.y);
    a4 += bf16lo(u.z); a5 += bf16hi(u.z);
    a6 += bf16lo(u.w); a7 += bf16hi(u.w);
  }
  red[s][q][0]=a0; red[s][q][1]=a1; red[s][q][2]=a2; red[s][q][3]=a3;
  red[s][q][4]=a4; red[s][q][5]=a5; red[s][q][6]=a6; red[s][q][7]=a7;
  __syncthreads();

  if (t < 32) {
    const int q2 = t >> 3, e = t & 7;
    float p = 0.f;
    for (int s2 = 0; s2 < 64; ++s2) p += red[s2][q2][e];
    p = p * (1.0f / 64.0f) + bias[o * 32 + q2 * 8 + e];
    float ns = p * p;                          // squash over 32-lane a-group
    ns += __shfl_xor(ns, 1);  ns += __shfl_xor(ns, 2);
    ns += __shfl_xor(ns, 4);  ns += __shfl_xor(ns, 8);
    ns += __shfl_xor(ns, 16);
    act[(size_t)b * J_ + o * 32 + q2 * 8 + e] = p * sqrtf(ns) / (1.0f + ns);
  }
}

// -------------------------------------------------------------------------
// route_kernel<PASS> v2 (PASS = 1,2): 256-thr blocks, 2 b x 8 i x all j,
// grid 2048 (= 256 i-slabs x 8 b-pairs) -> 8 blocks/CU: one block's softmax
// barriers hide under 7 other blocks. 8 j/thread via uint4 (16 B/lane).
// PASS2 logits prefetched at il top (L2 latency hides under dist compute);
// PASS1 logits written after barrier 2 (drains during next il's dist).
// Live regs ~56 < 64 budget.
// -------------------------------------------------------------------------
template<int PASS>
__global__ __launch_bounds__(256) void route_kernel(
    const uint4* __restrict__ votes4, const float* __restrict__ act_in,
    float* __restrict__ part, float* __restrict__ logits)
{
  __shared__ float d_lds[128];                 // [bb][o]
  __shared__ float r_lds[128];

  const int t = threadIdx.x;
  const int islab = blockIdx.x >> 3, bq = blockIdx.x & 7;
  const int i0 = islab * 8;
  const int o = t >> 2, l4 = t & 3;            // 4 threads per o, 8 j each
  const float4* __restrict__ actq = (const float4*)act_in;

  float4 av00 = actq[(size_t)(bq * 2 + 0) * 512 + 2 * t];
  float4 av01 = actq[(size_t)(bq * 2 + 0) * 512 + 2 * t + 1];
  float4 av10 = actq[(size_t)(bq * 2 + 1) * 512 + 2 * t];
  float4 av11 = actq[(size_t)(bq * 2 + 1) * 512 + 2 * t + 1];

  float4 ac00 = make_float4(0,0,0,0), ac01 = make_float4(0,0,0,0);
  float4 ac10 = make_float4(0,0,0,0), ac11 = make_float4(0,0,0,0);

  for (int il = 0; il < 8; ++il) {
    const int i = i0 + il;
    float lgv = 0.f;
    if (PASS == 2 && t < 128)                   // prefetch: hides under dist
      lgv = logits[((size_t)(bq * 2 + (t >> 6)) * I_ + i) * O_ + (t & 63)];

    const uint4* __restrict__ vo =
        votes4 + (size_t)i * 4096 + (size_t)(bq * 2) * 256 + t;
    uint4 v0 = vo[0];
    uint4 v1 = vo[256];

    // distances: full 8-j dot in-thread, then 2-step xor over the 4-group
    float c0 = bf16lo(v0.x)*av00.x + bf16hi(v0.x)*av00.y
             + bf16lo(v0.y)*av00.z + bf16hi(v0.y)*av00.w
             + bf16lo(v0.z)*av01.x + bf16hi(v0.z)*av01.y
             + bf16lo(v0.w)*av01.z + bf16hi(v0.w)*av01.w;
    c0 += __shfl_xor(c0, 1);  c0 += __shfl_xor(c0, 2);
    float c1 = bf16lo(v1.x)*av10.x + bf16hi(v1.x)*av10.y
             + bf16lo(v1.y)*av10.z + bf16hi(v1.y)*av10.w
             + bf16lo(v1.z)*av11.x + bf16hi(v1.z)*av11.y
             + bf16lo(v1.w)*av11.z + bf16hi(v1.w)*av11.w;
    c1 += __shfl_xor(c1, 1);  c1 += __shfl_xor(c1, 2);
    if (l4 == 0) d_lds[o]      = c0;
    if (l4 == 1) d_lds[64 + o] = c1;
    __syncthreads();

    // softmax over o: waves 0-1, one (bb) each; lane = o
    float ellsave = 0.f;
    if (t < 128) {
      float ell = d_lds[t];
      if (PASS == 2) ell += lgv;
      ellsave = ell;
      float m = ell;
      m = fmaxf(m, __shfl_xor(m, 32)); m = fmaxf(m, __shfl_xor(m, 16));
      m = fmaxf(m, __shfl_xor(m, 8));  m = fmaxf(m, __shfl_xor(m, 4));
      m = fmaxf(m, __shfl_xor(m, 2));  m = fmaxf(m, __shfl_xor(m, 1));
      float e = __expf(ell - m);
      float sd = e;
      sd += __shfl_xor(sd, 32); sd += __shfl_xor(sd, 16); sd += __shfl_xor(sd, 8);
      sd += __shfl_xor(sd, 4);  sd += __shfl_xor(sd, 2);  sd += __shfl_xor(sd, 1);
      r_lds[t] = e / sd;
    }
    __syncthreads();

    if (PASS == 1 && t < 128)                   // deferred: drains next il
      logits[((size_t)(bq * 2 + (t >> 6)) * I_ + i) * O_ + (t & 63)] = ellsave;

    float r0 = r_lds[o], r1 = r_lds[64 + o];
    ac00.x = fmaf(r0, bf16lo(v0.x), ac00.x); ac00.y = fmaf(r0, bf16hi(v0.x), ac00.y);
    ac00.z = fmaf(r0, bf16lo(v0.y), ac00.z); ac00.w = fmaf(r0, bf16hi(v0.y), ac00.w);
    ac01.x = fmaf(r0, bf16lo(v0.z), ac01.x); ac01.y = fmaf(r0, bf16hi(v0.z), ac01.y);
    ac01.z = fmaf(r0, bf16lo(v0.w), ac01.z); ac01.w = fmaf(r0, bf16hi(v0.w), ac01.w);
    ac10.x = fmaf(r1, bf16lo(v1.x), ac10.x); ac10.y = fmaf(r1, bf16hi(v1.x), ac10.y);
    ac10.z = fmaf(r1, bf16lo(v1.y), ac10.z); ac10.w = fmaf(r1, bf16hi(v1.y), ac10.w);
    ac11.x = fmaf(r1, bf16lo(v1.z), ac11.x); ac11.y = fmaf(r1, bf16hi(v1.z), ac11.y);
    ac11.z = fmaf(r1, bf16lo(v1.w), ac11.z); ac11.w = fmaf(r1, bf16hi(v1.w), ac11.w);
  }

  // part float layout: islab*32768 + b*2048 + j  (float4: islab*8192 + b*512 + j/4)
  float4* __restrict__ po =
      (float4*)part + (size_t)islab * 8192 + (size_t)(bq * 2) * 512 + 2 * t;
  po[0]   = ac00;  po[1]   = ac01;
  po[512] = ac10;  po[513] = ac11;
}

// -------------------------------------------------------------------------
// reduce_squash v2: one block per (b,o): grid 1024 (4 blocks/CU). Thread
// (s=t>>3, q=t&7) loads 8 float4 over slabs s + 32k; LDS tree; 8-lane squash.
// -------------------------------------------------------------------------
__global__ __launch_bounds__(256) void reduce_squash(
    const float* __restrict__ part, const float* __restrict__ bias,
    float* __restrict__ out)
{
  __shared__ float4 red[32][8];                // 4 KB
  const int b = blockIdx.x >> 6, o = blockIdx.x & 63;
  const int t = threadIdx.x, s = t >> 3, q = t & 7;
  const float4* __restrict__ base =
      (const float4*)part + (size_t)b * 512 + o * 8 + q;

  float4 acc = make_float4(0.f, 0.f, 0.f, 0.f);
  #pragma unroll
  for (int k = 0; k < 8; ++k) {
    float4 v = base[(size_t)(s + 32 * k) * 8192];
    acc.x += v.x; acc.y += v.y; acc.z += v.z; acc.w += v.w;
  }
  red[s][q] = acc;
  __syncthreads();

  if (t < 8) {
    float4 p = make_float4(0.f, 0.f, 0.f, 0.f);
    for (int s2 = 0; s2 < 32; ++s2) {
      float4 v = red[s2][t];
      p.x += v.x; p.y += v.y; p.z += v.z; p.w += v.w;
    }
    float4 bq4 = ((const float4*)bias)[o * 8 + t];
    p.x += bq4.x; p.y += bq4.y; p.z += bq4.z; p.w += bq4.w;
    float ns = p.x*p.x + p.y*p.y + p.z*p.z + p.w*p.w;
    ns += __shfl_xor(ns, 1);  ns += __shfl_xor(ns, 2);  ns += __shfl_xor(ns, 4);
    float sc = sqrtf(ns) / (1.0f + ns);
    ((float4*)out)[(size_t)b * 512 + o * 8 + t] =
        make_float4(p.x*sc, p.y*sc, p.z*sc, p.w*sc);
  }
}

// -------------------------------------------------------------------------
// FALLBACK (ws too small): W-streaming pass kernel, part at islab*32768 +
// b*2048 + j (same layout reduce_squash v2 expects).
// -------------------------------------------------------------------------
template<int PASS>
__global__ __launch_bounds__(1024) void fb_pass_kernel(
    const float* __restrict__ x, const float* __restrict__ W,
    const float* __restrict__ act_in, float* __restrict__ part,
    float* __restrict__ logits)
{
  __shared__ float x_lds[8 * B_ * AIN_];
  __shared__ float d_lds[8 * O_];
  __shared__ float r_lds[8 * O_];
  const int tid = threadIdx.x, blk = blockIdx.x, i0 = blk * 8;
  for (int e = tid; e < 8 * B_ * AIN_; e += 1024) {
    int b = e >> 7, il = (e >> 4) & 7, a = e & 15;
    x_lds[il * 256 + b * 16 + a] =
        x[(size_t)b * (I_ * AIN_) + (size_t)(i0 + il) * AIN_ + a];
  }
  __syncthreads();
  const int og = tid >> 4, lg = tid & 15;
  float2 acc[16];
  #pragma unroll
  for (int b = 0; b < 16; ++b) acc[b] = make_float2(0.f, 0.f);
  const float2* __restrict__ Wq   = (const float2*)W;
  const float2* __restrict__ actq = (const float2*)act_in;
  for (int il = 0; il < 8; ++il) {
    const int i = i0 + il;
    const float2* __restrict__ Wi = Wq + (size_t)i * (AIN_ * JP_);
    const float4* __restrict__ xq = (const float4*)x_lds + il * 64;
    for (int h = 0; h < 2; ++h) {
      float2 v[8];
      #pragma unroll
      for (int bb = 0; bb < 8; ++bb) v[bb] = make_float2(0.f, 0.f);
      #pragma unroll
      for (int a4 = 0; a4 < 4; ++a4) {
        float2 w0 = Wi[(size_t)(a4 * 4 + 0) * JP_ + tid];
        float2 w1 = Wi[(size_t)(a4 * 4 + 1) * JP_ + tid];
        float2 w2 = Wi[(size_t)(a4 * 4 + 2) * JP_ + tid];
        float2 w3 = Wi[(size_t)(a4 * 4 + 3) * JP_ + tid];
        #pragma unroll
        for (int bb = 0; bb < 8; ++bb) {
          float4 xv = xq[(h * 8 + bb) * 4 + a4];
          v[bb].x = fmaf(xv.x, w0.x, v[bb].x); v[bb].y = fmaf(xv.x, w0.y, v[bb].y);
          v[bb].x = fmaf(xv.y, w1.x, v[bb].x); v[bb].y = fmaf(xv.y, w1.y, v[bb].y);
          v[bb].x = fmaf(xv.z, w2.x, v[bb].x); v[bb].y = fmaf(xv.z, w2.y, v[bb].y);
          v[bb].x = fmaf(xv.w, w3.x, v[bb].x); v[bb].y = fmaf(xv.w, w3.y, v[bb].y);
        }
      }
      if (PASS == 0) {
        #pragma unroll
        for (int bb = 0; bb < 8; ++bb) {
          acc[h * 8 + bb].x += v[bb].x; acc[h * 8 + bb].y += v[bb].y;
        }
      } else {
        #pragma unroll
        for (int bb = 0; bb < 8; ++bb) {
          const int b = h * 8 + bb;
          float2 avv = actq[(size_t)b * JP_ + tid];
          float c = v[bb].x * avv.x + v[bb].y * avv.y;
          c += __shfl_xor(c, 1); c += __shfl_xor(c, 2);
          c += __shfl_xor(c, 4); c += __shfl_xor(c, 8);
          if (lg == bb) d_lds[bb * 64 + og] = c;
        }
        __syncthreads();
        if (tid < 512) {
          const int bb2 = tid >> 6, o2 = tid & 63;
          const int b2  = h * 8 + bb2;
          float ell = d_lds[tid];
          if (PASS == 2) ell += logits[((size_t)b2 * I_ + i) * O_ + o2];
          if (PASS == 1) logits[((size_t)b2 * I_ + i) * O_ + o2] = ell;
          float m = ell;
          m = fmaxf(m, __shfl_xor(m, 32)); m = fmaxf(m, __shfl_xor(m, 16));
          m = fmaxf(m, __shfl_xor(m, 8));  m = fmaxf(m, __shfl_xor(m, 4));
          m = fmaxf(m, __shfl_xor(m, 2));  m = fmaxf(m, __shfl_xor(m, 1));
          float e = __expf(ell - m);
          float s = e;
          s += __shfl_xor(s, 32); s += __shfl_xor(s, 16); s += __shfl_xor(s, 8);
          s += __shfl_xor(s, 4);  s += __shfl_xor(s, 2);  s += __shfl_xor(s, 1);
          r_lds[tid] = e / s;
        }
        __syncthreads();
        #pragma unroll
        for (int bb = 0; bb < 8; ++bb) {
          float r = r_lds[bb * 64 + og];
          acc[h * 8 + bb].x = fmaf(r, v[bb].x, acc[h * 8 + bb].x);
          acc[h * 8 + bb].y = fmaf(r, v[bb].y, acc[h * 8 + bb].y);
        }
      }
    }
  }
  const float sc = (PASS == 0) ? (1.0f / 64.0f) : 1.0f;
  #pragma unroll
  for (int b = 0; b < 16; ++b) {
    float2* __restrict__ po = (float2*)part +
        (size_t)blk * (B_ * JP_) + (size_t)b * JP_ + tid;
    *po = make_float2(acc[b].x * sc, acc[b].y * sc);
  }
}

// -------------------------------------------------------------------------
extern "C" void kernel_launch(void* const* d_in, const int* in_sizes, int n_in,
                              void* d_out, int out_size, void* d_ws, size_t ws_size,
                              hipStream_t stream) {
  const float* x    = (const float*)d_in[0];
  const float* W    = (const float*)d_in[1];
  const float* bias = (const float*)d_in[2];
  float* out = (float*)d_out;

  float*    part   = (float*)d_ws;                        // 32 MB
  float*    act    = part + (size_t)256 * (B_ * J_);      // 128 KB
  float*    logits = act + (B_ * J_);                     // 8 MB
  unsigned* votes  = (unsigned*)(logits + (size_t)B_ * I_ * O_);  // 134 MB
  const size_t need = ((size_t)256 * B_ * J_ + B_ * J_ + (size_t)B_ * I_ * O_) * 4
                    + (size_t)I_ * B_ * JP_ * 4;

  if (ws_size >= need) {
    votes_kernel<<<1024, 512, 0, stream>>>(x, W, votes);
    reduce0_kernel<<<1024, 256, 0, stream>>>((const uint4*)votes, bias, act);
    route_kernel<1><<<2048, 256, 0, stream>>>((const uint4*)votes, act, part, logits);
    reduce_squash<<<1024, 256, 0, stream>>>(part, bias, act);
    route_kernel<2><<<2048, 256, 0, stream>>>((const uint4*)votes, act, part, logits);
    reduce_squash<<<1024, 256, 0, stream>>>(part, bias, out);
  } else {
    fb_pass_kernel<0><<<256, 1024, 0, stream>>>(x, W, act, part, logits);
    reduce_squash<<<1024, 256, 0, stream>>>(part, bias, act);
    fb_pass_kernel<1><<<256, 1024, 0, stream>>>(x, W, act, part, logits);
    reduce_squash<<<1024, 256, 0, stream>>>(part, bias, act);
    fb_pass_kernel<2><<<256, 1024, 0, stream>>>(x, W, act, part, logits);
    reduce_squash<<<1024, 256, 0, stream>>>(part, bias, out);
  }
}

// Round 10
// 180.791 us; speedup vs baseline: 1.3142x; 1.0535x over previous
//
#include <hip/hip_runtime.h>
#include <math.h>

#define B_   16
#define I_   2048
#define AIN_ 16
#define O_   64
#define J_   2048     // O*A_OUT
#define JP_  1024     // j as packed bf16x2 / float2 columns

// bf16 pack/unpack (RNE). Inputs finite -> no NaN handling needed.
__device__ __forceinline__ unsigned bf16rne(float f) {
  unsigned u = __float_as_uint(f);
  return (u + 0x7FFFu + ((u >> 16) & 1u)) >> 16;
}
__device__ __forceinline__ float bf16lo(unsigned p) { return __uint_as_float(p << 16); }
__device__ __forceinline__ float bf16hi(unsigned p) { return __uint_as_float(p & 0xFFFF0000u); }

// non-temporal float2 load (W is a read-once 268 MB stream; keep it out of
// L3 so the 134 MB votes working set stays resident for the route passes)
__device__ __forceinline__ float2 ntload2(const float2* p) {
  union { double d; float2 f; } u;
  u.d = __builtin_nontemporal_load((const double*)p);
  return u.f;
}

// -------------------------------------------------------------------------
// votes_p0_kernel: votes[i,b,jp] (packed bf16x2) AND pass-0 partials
// (uniform route=1/64) -> part0. Eliminates round-9's reduce0 (a full
// 134 MB votes re-read one kernel after votes sat in registers).
// 256-thr blocks + waves_per_eu(4,4): at 4 waves/block the constraint is
// satisfiable -> 128-VGPR budget (rounds 1-3 showed 512/1024-thr blocks
// get pinned to 64). Live regs ~80: v[16]f2 + acc[16]f2 + w + addr.
// Grid 1024 = 256 i-slabs(8 i) x 4 j-tiles(512 j); 2 j/thread float2 W
// loads (round 5's fold failed via 1-j/4B layout, not the fold itself).
// W read EXACTLY once (nt).
// -------------------------------------------------------------------------
__global__ __launch_bounds__(256)
__attribute__((amdgpu_waves_per_eu(4, 4)))
void votes_p0_kernel(
    const float* __restrict__ x, const float* __restrict__ W,
    unsigned* __restrict__ votes, float* __restrict__ part0)
{
  __shared__ float x_lds[8 * B_ * AIN_];       // 8 KB, [il][b][a]
  const int tid = threadIdx.x;
  const int islab = blockIdx.x >> 2, jt = blockIdx.x & 3;
  const int i0 = islab * 8;

  for (int e = tid; e < 8 * B_ * AIN_; e += 256) {
    int il = e >> 8, b = (e >> 4) & 15, a = e & 15;
    x_lds[il * 256 + b * 16 + a] =
        x[(size_t)b * (I_ * AIN_) + (size_t)(i0 + il) * AIN_ + a];
  }
  __syncthreads();

  const float2* __restrict__ Wq = (const float2*)W;
  const int jp = jt * 256 + tid;               // float2 column 0..1023

  float2 acc[16];
  #pragma unroll
  for (int b = 0; b < 16; ++b) acc[b] = make_float2(0.f, 0.f);

  for (int il = 0; il < 8; ++il) {
    const int i = i0 + il;
    const float2* __restrict__ Wi = Wq + (size_t)i * (AIN_ * JP_) + jp;
    const float2* __restrict__ xq = (const float2*)x_lds + il * 128; // [b][a2]

    float2 v[16];
    #pragma unroll
    for (int b = 0; b < 16; ++b) v[b] = make_float2(0.f, 0.f);

    #pragma unroll
    for (int a2 = 0; a2 < 8; ++a2) {
      float2 w0 = ntload2(Wi + (size_t)(2 * a2 + 0) * JP_);
      float2 w1 = ntload2(Wi + (size_t)(2 * a2 + 1) * JP_);
      #pragma unroll
      for (int b = 0; b < 16; ++b) {
        float2 xv = xq[b * 8 + a2];            // LDS broadcast
        v[b].x = fmaf(xv.x, w0.x, v[b].x);
        v[b].y = fmaf(xv.x, w0.y, v[b].y);
        v[b].x = fmaf(xv.y, w1.x, v[b].x);
        v[b].y = fmaf(xv.y, w1.y, v[b].y);
      }
    }

    unsigned* __restrict__ vo = votes + (size_t)i * (B_ * JP_) + jp;
    #pragma unroll
    for (int b = 0; b < 16; ++b) {
      vo[(size_t)b * JP_] = bf16rne(v[b].x) | (bf16rne(v[b].y) << 16);
      acc[b].x += v[b].x;  acc[b].y += v[b].y;
    }
  }

  // part0 float layout: [slab = islab*4 + jt][16 b][512 j]
  float2* __restrict__ po =
      (float2*)part0 + (size_t)blockIdx.x * (B_ * 256) + tid;
  #pragma unroll
  for (int b = 0; b < 16; ++b)
    po[(size_t)b * 256] = make_float2(acc[b].x * (1.0f / 64.0f),
                                      acc[b].y * (1.0f / 64.0f));
}

// -------------------------------------------------------------------------
// reduce_squash0: act0 = squash( sum over 256 i-slabs of part0 + bias ).
// part0 layout [islab*4 + jt][16 b][512 j]. One block per (b,o), grid 1024
// (4 blocks/CU). Thread (s=t>>3, q=t&7) loads 8 float4 over islab = s+32k.
// -------------------------------------------------------------------------
__global__ __launch_bounds__(256) void reduce_squash0(
    const float* __restrict__ part0, const float* __restrict__ bias,
    float* __restrict__ act)
{
  __shared__ float4 red[32][8];                // 4 KB
  const int b = blockIdx.x >> 6, o = blockIdx.x & 63;
  const int t = threadIdx.x, s = t >> 3, q = t & 7;
  const int jt = o >> 4;                       // (o*32)>>9
  const float4* __restrict__ base =
      (const float4*)part0 + (size_t)(jt * 16 + b) * 128 + (((o * 32) & 511) >> 2) + q;

  float4 acc = make_float4(0.f, 0.f, 0.f, 0.f);
  #pragma unroll
  for (int k = 0; k < 8; ++k) {
    float4 v = base[(size_t)(s + 32 * k) * 8192];   // islab stride = 4*16*128
    acc.x += v.x; acc.y += v.y; acc.z += v.z; acc.w += v.w;
  }
  red[s][q] = acc;
  __syncthreads();

  if (t < 8) {
    float4 p = make_float4(0.f, 0.f, 0.f, 0.f);
    for (int s2 = 0; s2 < 32; ++s2) {
      float4 v = red[s2][t];
      p.x += v.x; p.y += v.y; p.z += v.z; p.w += v.w;
    }
    float4 bq4 = ((const float4*)bias)[o * 8 + t];
    p.x = p.x * (1.0f / 64.0f) * 64.0f + bq4.x;  // (already scaled in kernel)
    // NOTE: partials were pre-scaled by 1/64 in votes_p0; just add bias:
    p.x = p.x - bq4.x + bq4.x;                   // no-op guard (keep simple)
    p.y += bq4.y; p.z += bq4.z; p.w += bq4.w;
    float ns = p.x*p.x + p.y*p.y + p.z*p.z + p.w*p.w;
    ns += __shfl_xor(ns, 1);  ns += __shfl_xor(ns, 2);  ns += __shfl_xor(ns, 4);
    float sc = sqrtf(ns) / (1.0f + ns);
    ((float4*)act)[(size_t)b * 512 + o * 8 + t] =
        make_float4(p.x*sc, p.y*sc, p.z*sc, p.w*sc);
  }
}

// -------------------------------------------------------------------------
// route_kernel<PASS> (PASS = 1,2) — unchanged from round 9 (proven).
// 256-thr blocks, 2 b x 8 i x all j, grid 2048 -> 8 blocks/CU.
// -------------------------------------------------------------------------
template<int PASS>
__global__ __launch_bounds__(256) void route_kernel(
    const uint4* __restrict__ votes4, const float* __restrict__ act_in,
    float* __restrict__ part, float* __restrict__ logits)
{
  __shared__ float d_lds[128];                 // [bb][o]
  __shared__ float r_lds[128];

  const int t = threadIdx.x;
  const int islab = blockIdx.x >> 3, bq = blockIdx.x & 7;
  const int i0 = islab * 8;
  const int o = t >> 2, l4 = t & 3;            // 4 threads per o, 8 j each
  const float4* __restrict__ actq = (const float4*)act_in;

  float4 av00 = actq[(size_t)(bq * 2 + 0) * 512 + 2 * t];
  float4 av01 = actq[(size_t)(bq * 2 + 0) * 512 + 2 * t + 1];
  float4 av10 = actq[(size_t)(bq * 2 + 1) * 512 + 2 * t];
  float4 av11 = actq[(size_t)(bq * 2 + 1) * 512 + 2 * t + 1];

  float4 ac00 = make_float4(0,0,0,0), ac01 = make_float4(0,0,0,0);
  float4 ac10 = make_float4(0,0,0,0), ac11 = make_float4(0,0,0,0);

  for (int il = 0; il < 8; ++il) {
    const int i = i0 + il;
    float lgv = 0.f;
    if (PASS == 2 && t < 128)                   // prefetch: hides under dist
      lgv = logits[((size_t)(bq * 2 + (t >> 6)) * I_ + i) * O_ + (t & 63)];

    const uint4* __restrict__ vo =
        votes4 + (size_t)i * 4096 + (size_t)(bq * 2) * 256 + t;
    uint4 v0 = vo[0];
    uint4 v1 = vo[256];

    // distances: full 8-j dot in-thread, then 2-step xor over the 4-group
    float c0 = bf16lo(v0.x)*av00.x + bf16hi(v0.x)*av00.y
             + bf16lo(v0.y)*av00.z + bf16hi(v0.y)*av00.w
             + bf16lo(v0.z)*av01.x + bf16hi(v0.z)*av01.y
             + bf16lo(v0.w)*av01.z + bf16hi(v0.w)*av01.w;
    c0 += __shfl_xor(c0, 1);  c0 += __shfl_xor(c0, 2);
    float c1 = bf16lo(v1.x)*av10.x + bf16hi(v1.x)*av10.y
             + bf16lo(v1.y)*av10.z + bf16hi(v1.y)*av10.w
             + bf16lo(v1.z)*av11.x + bf16hi(v1.z)*av11.y
             + bf16lo(v1.w)*av11.z + bf16hi(v1.w)*av11.w;
    c1 += __shfl_xor(c1, 1);  c1 += __shfl_xor(c1, 2);
    if (l4 == 0) d_lds[o]      = c0;
    if (l4 == 1) d_lds[64 + o] = c1;
    __syncthreads();

    // softmax over o: waves 0-1, one (bb) each; lane = o
    float ellsave = 0.f;
    if (t < 128) {
      float ell = d_lds[t];
      if (PASS == 2) ell += lgv;
      ellsave = ell;
      float m = ell;
      m = fmaxf(m, __shfl_xor(m, 32)); m = fmaxf(m, __shfl_xor(m, 16));
      m = fmaxf(m, __shfl_xor(m, 8));  m = fmaxf(m, __shfl_xor(m, 4));
      m = fmaxf(m, __shfl_xor(m, 2));  m = fmaxf(m, __shfl_xor(m, 1));
      float e = __expf(ell - m);
      float sd = e;
      sd += __shfl_xor(sd, 32); sd += __shfl_xor(sd, 16); sd += __shfl_xor(sd, 8);
      sd += __shfl_xor(sd, 4);  sd += __shfl_xor(sd, 2);  sd += __shfl_xor(sd, 1);
      r_lds[t] = e / sd;
    }
    __syncthreads();

    if (PASS == 1 && t < 128)                   // deferred: drains next il
      logits[((size_t)(bq * 2 + (t >> 6)) * I_ + i) * O_ + (t & 63)] = ellsave;

    float r0 = r_lds[o], r1 = r_lds[64 + o];
    ac00.x = fmaf(r0, bf16lo(v0.x), ac00.x); ac00.y = fmaf(r0, bf16hi(v0.x), ac00.y);
    ac00.z = fmaf(r0, bf16lo(v0.y), ac00.z); ac00.w = fmaf(r0, bf16hi(v0.y), ac00.w);
    ac01.x = fmaf(r0, bf16lo(v0.z), ac01.x); ac01.y = fmaf(r0, bf16hi(v0.z), ac01.y);
    ac01.z = fmaf(r0, bf16lo(v0.w), ac01.z); ac01.w = fmaf(r0, bf16hi(v0.w), ac01.w);
    ac10.x = fmaf(r1, bf16lo(v1.x), ac10.x); ac10.y = fmaf(r1, bf16hi(v1.x), ac10.y);
    ac10.z = fmaf(r1, bf16lo(v1.y), ac10.z); ac10.w = fmaf(r1, bf16hi(v1.y), ac10.w);
    ac11.x = fmaf(r1, bf16lo(v1.z), ac11.x); ac11.y = fmaf(r1, bf16hi(v1.z), ac11.y);
    ac11.z = fmaf(r1, bf16lo(v1.w), ac11.z); ac11.w = fmaf(r1, bf16hi(v1.w), ac11.w);
  }

  // part float layout: islab*32768 + b*2048 + j  (float4: islab*8192 + b*512 + j/4)
  float4* __restrict__ po =
      (float4*)part + (size_t)islab * 8192 + (size_t)(bq * 2) * 512 + 2 * t;
  po[0]   = ac00;  po[1]   = ac01;
  po[512] = ac10;  po[513] = ac11;
}

// -------------------------------------------------------------------------
// reduce_squash: unchanged from round 9. One block per (b,o), grid 1024.
// part float layout: islab*32768 + b*2048 + j.
// -------------------------------------------------------------------------
__global__ __launch_bounds__(256) void reduce_squash(
    const float* __restrict__ part, const float* __restrict__ bias,
    float* __restrict__ out)
{
  __shared__ float4 red[32][8];                // 4 KB
  const int b = blockIdx.x >> 6, o = blockIdx.x & 63;
  const int t = threadIdx.x, s = t >> 3, q = t & 7;
  const float4* __restrict__ base =
      (const float4*)part + (size_t)b * 512 + o * 8 + q;

  float4 acc = make_float4(0.f, 0.f, 0.f, 0.f);
  #pragma unroll
  for (int k = 0; k < 8; ++k) {
    float4 v = base[(size_t)(s + 32 * k) * 8192];
    acc.x += v.x; acc.y += v.y; acc.z += v.z; acc.w += v.w;
  }
  red[s][q] = acc;
  __syncthreads();

  if (t < 8) {
    float4 p = make_float4(0.f, 0.f, 0.f, 0.f);
    for (int s2 = 0; s2 < 32; ++s2) {
      float4 v = red[s2][t];
      p.x += v.x; p.y += v.y; p.z += v.z; p.w += v.w;
    }
    float4 bq4 = ((const float4*)bias)[o * 8 + t];
    p.x += bq4.x; p.y += bq4.y; p.z += bq4.z; p.w += bq4.w;
    float ns = p.x*p.x + p.y*p.y + p.z*p.z + p.w*p.w;
    ns += __shfl_xor(ns, 1);  ns += __shfl_xor(ns, 2);  ns += __shfl_xor(ns, 4);
    float sc = sqrtf(ns) / (1.0f + ns);
    ((float4*)out)[(size_t)b * 512 + o * 8 + t] =
        make_float4(p.x*sc, p.y*sc, p.z*sc, p.w*sc);
  }
}

// -------------------------------------------------------------------------
// FALLBACK (ws too small): W-streaming pass kernel, part at islab*32768 +
// b*2048 + j (same layout reduce_squash expects).
// -------------------------------------------------------------------------
template<int PASS>
__global__ __launch_bounds__(1024) void fb_pass_kernel(
    const float* __restrict__ x, const float* __restrict__ W,
    const float* __restrict__ act_in, float* __restrict__ part,
    float* __restrict__ logits)
{
  __shared__ float x_lds[8 * B_ * AIN_];
  __shared__ float d_lds[8 * O_];
  __shared__ float r_lds[8 * O_];
  const int tid = threadIdx.x, blk = blockIdx.x, i0 = blk * 8;
  for (int e = tid; e < 8 * B_ * AIN_; e += 1024) {
    int b = e >> 7, il = (e >> 4) & 7, a = e & 15;
    x_lds[il * 256 + b * 16 + a] =
        x[(size_t)b * (I_ * AIN_) + (size_t)(i0 + il) * AIN_ + a];
  }
  __syncthreads();
  const int og = tid >> 4, lg = tid & 15;
  float2 acc[16];
  #pragma unroll
  for (int b = 0; b < 16; ++b) acc[b] = make_float2(0.f, 0.f);
  const float2* __restrict__ Wq   = (const float2*)W;
  const float2* __restrict__ actq = (const float2*)act_in;
  for (int il = 0; il < 8; ++il) {
    const int i = i0 + il;
    const float2* __restrict__ Wi = Wq + (size_t)i * (AIN_ * JP_);
    const float4* __restrict__ xq = (const float4*)x_lds + il * 64;
    for (int h = 0; h < 2; ++h) {
      float2 v[8];
      #pragma unroll
      for (int bb = 0; bb < 8; ++bb) v[bb] = make_float2(0.f, 0.f);
      #pragma unroll
      for (int a4 = 0; a4 < 4; ++a4) {
        float2 w0 = Wi[(size_t)(a4 * 4 + 0) * JP_ + tid];
        float2 w1 = Wi[(size_t)(a4 * 4 + 1) * JP_ + tid];
        float2 w2 = Wi[(size_t)(a4 * 4 + 2) * JP_ + tid];
        float2 w3 = Wi[(size_t)(a4 * 4 + 3) * JP_ + tid];
        #pragma unroll
        for (int bb = 0; bb < 8; ++bb) {
          float4 xv = xq[(h * 8 + bb) * 4 + a4];
          v[bb].x = fmaf(xv.x, w0.x, v[bb].x); v[bb].y = fmaf(xv.x, w0.y, v[bb].y);
          v[bb].x = fmaf(xv.y, w1.x, v[bb].x); v[bb].y = fmaf(xv.y, w1.y, v[bb].y);
          v[bb].x = fmaf(xv.z, w2.x, v[bb].x); v[bb].y = fmaf(xv.z, w2.y, v[bb].y);
          v[bb].x = fmaf(xv.w, w3.x, v[bb].x); v[bb].y = fmaf(xv.w, w3.y, v[bb].y);
        }
      }
      if (PASS == 0) {
        #pragma unroll
        for (int bb = 0; bb < 8; ++bb) {
          acc[h * 8 + bb].x += v[bb].x; acc[h * 8 + bb].y += v[bb].y;
        }
      } else {
        #pragma unroll
        for (int bb = 0; bb < 8; ++bb) {
          const int b = h * 8 + bb;
          float2 avv = actq[(size_t)b * JP_ + tid];
          float c = v[bb].x * avv.x + v[bb].y * avv.y;
          c += __shfl_xor(c, 1); c += __shfl_xor(c, 2);
          c += __shfl_xor(c, 4); c += __shfl_xor(c, 8);
          if (lg == bb) d_lds[bb * 64 + og] = c;
        }
        __syncthreads();
        if (tid < 512) {
          const int bb2 = tid >> 6, o2 = tid & 63;
          const int b2  = h * 8 + bb2;
          float ell = d_lds[tid];
          if (PASS == 2) ell += logits[((size_t)b2 * I_ + i) * O_ + o2];
          if (PASS == 1) logits[((size_t)b2 * I_ + i) * O_ + o2] = ell;
          float m = ell;
          m = fmaxf(m, __shfl_xor(m, 32)); m = fmaxf(m, __shfl_xor(m, 16));
          m = fmaxf(m, __shfl_xor(m, 8));  m = fmaxf(m, __shfl_xor(m, 4));
          m = fmaxf(m, __shfl_xor(m, 2));  m = fmaxf(m, __shfl_xor(m, 1));
          float e = __expf(ell - m);
          float s = e;
          s += __shfl_xor(s, 32); s += __shfl_xor(s, 16); s += __shfl_xor(s, 8);
          s += __shfl_xor(s, 4);  s += __shfl_xor(s, 2);  s += __shfl_xor(s, 1);
          r_lds[tid] = e / s;
        }
        __syncthreads();
        #pragma unroll
        for (int bb = 0; bb < 8; ++bb) {
          float r = r_lds[bb * 64 + og];
          acc[h * 8 + bb].x = fmaf(r, v[bb].x, acc[h * 8 + bb].x);
          acc[h * 8 + bb].y = fmaf(r, v[bb].y, acc[h * 8 + bb].y);
        }
      }
    }
  }
  const float sc = (PASS == 0) ? (1.0f / 64.0f) : 1.0f;
  #pragma unroll
  for (int b = 0; b < 16; ++b) {
    float2* __restrict__ po = (float2*)part +
        (size_t)blk * (B_ * JP_) + (size_t)b * JP_ + tid;
    *po = make_float2(acc[b].x * sc, acc[b].y * sc);
  }
}

// -------------------------------------------------------------------------
extern "C" void kernel_launch(void* const* d_in, const int* in_sizes, int n_in,
                              void* d_out, int out_size, void* d_ws, size_t ws_size,
                              hipStream_t stream) {
  const float* x    = (const float*)d_in[0];
  const float* W    = (const float*)d_in[1];
  const float* bias = (const float*)d_in[2];
  float* out = (float*)d_out;

  float*    part   = (float*)d_ws;                        // 32 MB (part0 aliases)
  float*    act    = part + (size_t)256 * (B_ * J_);      // 128 KB
  float*    logits = act + (B_ * J_);                     // 8 MB
  unsigned* votes  = (unsigned*)(logits + (size_t)B_ * I_ * O_);  // 134 MB
  const size_t need = ((size_t)256 * B_ * J_ + B_ * J_ + (size_t)B_ * I_ * O_) * 4
                    + (size_t)I_ * B_ * JP_ * 4;

  if (ws_size >= need) {
    votes_p0_kernel<<<1024, 256, 0, stream>>>(x, W, votes, part);
    reduce_squash0<<<1024, 256, 0, stream>>>(part, bias, act);
    route_kernel<1><<<2048, 256, 0, stream>>>((const uint4*)votes, act, part, logits);
    reduce_squash<<<1024, 256, 0, stream>>>(part, bias, act);
    route_kernel<2><<<2048, 256, 0, stream>>>((const uint4*)votes, act, part, logits);
    reduce_squash<<<1024, 256, 0, stream>>>(part, bias, out);
  } else {
    fb_pass_kernel<0><<<256, 1024, 0, stream>>>(x, W, act, part, logits);
    reduce_squash<<<1024, 256, 0, stream>>>(part, bias, act);
    fb_pass_kernel<1><<<256, 1024, 0, stream>>>(x, W, act, part, logits);
    reduce_squash<<<1024, 256, 0, stream>>>(part, bias, act);
    fb_pass_kernel<2><<<256, 1024, 0, stream>>>(x, W, act, part, logits);
    reduce_squash<<<1024, 256, 0, stream>>>(part, bias, out);
  }
}

// Round 11
// 165.375 us; speedup vs baseline: 1.4367x; 1.0932x over previous
//
#include <hip/hip_runtime.h>
#include <math.h>

#define B_   16
#define I_   2048
#define AIN_ 16
#define O_   64
#define J_   2048     // O*A_OUT
#define JP_  1024     // j as packed bf16x2 / float2 columns

// bf16 pack/unpack (RNE). Inputs finite -> no NaN handling needed.
__device__ __forceinline__ unsigned bf16rne(float f) {
  unsigned u = __float_as_uint(f);
  return (u + 0x7FFFu + ((u >> 16) & 1u)) >> 16;
}
__device__ __forceinline__ unsigned pk2(float a, float b) {
  return bf16rne(a) | (bf16rne(b) << 16);
}
__device__ __forceinline__ float bf16lo(unsigned p) { return __uint_as_float(p << 16); }
__device__ __forceinline__ float bf16hi(unsigned p) { return __uint_as_float(p & 0xFFFF0000u); }

// non-temporal float2 load (W is a read-once 268 MB stream; keep it out of
// L3 so the 134 MB votes working set stays resident for the route passes)
__device__ __forceinline__ float2 ntload2(const float2* p) {
  union { double d; float2 f; } u;
  u.d = __builtin_nontemporal_load((const double*)p);
  return u.f;
}

// -------------------------------------------------------------------------
// votes_p0_kernel: votes[i,b,jp] (packed bf16x2) AND pass-0 partials
// (uniform route=1/64) -> part0 as PACKED bf16x2 (16 MB, was 32 MB f32;
// partial ~0.02 magnitude -> bf16 rounding adds ~1e-4/slab, ~1e-3 final).
// 256-thr blocks + waves_per_eu(4,4) -> 128-VGPR budget (the recipe that
// made the fold work in round 10; 512/1024-thr blocks get pinned to 64).
// Grid 1024 = 256 i-slabs(8 i) x 4 j-tiles(512 j); 2 j/thread; W read
// EXACTLY once (nt). Live regs ~80.
// -------------------------------------------------------------------------
__global__ __launch_bounds__(256)
__attribute__((amdgpu_waves_per_eu(4, 4)))
void votes_p0_kernel(
    const float* __restrict__ x, const float* __restrict__ W,
    unsigned* __restrict__ votes, unsigned* __restrict__ part0)
{
  __shared__ float x_lds[8 * B_ * AIN_];       // 8 KB, [il][b][a]
  const int tid = threadIdx.x;
  const int islab = blockIdx.x >> 2, jt = blockIdx.x & 3;
  const int i0 = islab * 8;

  for (int e = tid; e < 8 * B_ * AIN_; e += 256) {
    int il = e >> 8, b = (e >> 4) & 15, a = e & 15;
    x_lds[il * 256 + b * 16 + a] =
        x[(size_t)b * (I_ * AIN_) + (size_t)(i0 + il) * AIN_ + a];
  }
  __syncthreads();

  const float2* __restrict__ Wq = (const float2*)W;
  const int jp = jt * 256 + tid;               // float2 column 0..1023

  float2 acc[16];
  #pragma unroll
  for (int b = 0; b < 16; ++b) acc[b] = make_float2(0.f, 0.f);

  for (int il = 0; il < 8; ++il) {
    const int i = i0 + il;
    const float2* __restrict__ Wi = Wq + (size_t)i * (AIN_ * JP_) + jp;
    const float2* __restrict__ xq = (const float2*)x_lds + il * 128; // [b][a2]

    float2 v[16];
    #pragma unroll
    for (int b = 0; b < 16; ++b) v[b] = make_float2(0.f, 0.f);

    #pragma unroll
    for (int a2 = 0; a2 < 8; ++a2) {
      float2 w0 = ntload2(Wi + (size_t)(2 * a2 + 0) * JP_);
      float2 w1 = ntload2(Wi + (size_t)(2 * a2 + 1) * JP_);
      #pragma unroll
      for (int b = 0; b < 16; ++b) {
        float2 xv = xq[b * 8 + a2];            // LDS broadcast
        v[b].x = fmaf(xv.x, w0.x, v[b].x);
        v[b].y = fmaf(xv.x, w0.y, v[b].y);
        v[b].x = fmaf(xv.y, w1.x, v[b].x);
        v[b].y = fmaf(xv.y, w1.y, v[b].y);
      }
    }

    unsigned* __restrict__ vo = votes + (size_t)i * (B_ * JP_) + jp;
    #pragma unroll
    for (int b = 0; b < 16; ++b) {
      vo[(size_t)b * JP_] = pk2(v[b].x, v[b].y);
      acc[b].x += v[b].x;  acc[b].y += v[b].y;
    }
  }

  // part0 packed layout: [slab = islab*4 + jt][16 b][256 uint (=512 j)]
  unsigned* __restrict__ po = part0 + (size_t)blockIdx.x * (B_ * 256) + tid;
  #pragma unroll
  for (int b = 0; b < 16; ++b)
    po[(size_t)b * 256] = pk2(acc[b].x * (1.0f / 64.0f),
                              acc[b].y * (1.0f / 64.0f));
}

// -------------------------------------------------------------------------
// reduce_squash0_bf: act0 = squash( sum over 256 i-slabs of bf16 part0
// + bias ). part0 layout [islab*4 + jt][16 b][256 uint]. One block per
// (b,o), grid 1024. Thread (s=t>>3, q=t&7) loads 8 uint2 over islab=s+32k.
// -------------------------------------------------------------------------
__global__ __launch_bounds__(256) void reduce_squash0_bf(
    const unsigned* __restrict__ part0, const float* __restrict__ bias,
    float* __restrict__ act)
{
  __shared__ float4 red[32][8];                // 4 KB
  const int b = blockIdx.x >> 6, o = blockIdx.x & 63;
  const int t = threadIdx.x, s = t >> 3, q = t & 7;
  const int jt = o >> 4;                       // j-tile of this o
  const int lu2 = (o & 15) * 8;                // local uint2 offset in slab row
  const uint2* __restrict__ base =
      (const uint2*)part0 + (size_t)jt * 2048 + (size_t)b * 128 + lu2 + q;

  float4 acc = make_float4(0.f, 0.f, 0.f, 0.f);
  #pragma unroll
  for (int k = 0; k < 8; ++k) {
    uint2 v = base[(size_t)(s + 32 * k) * 8192];   // islab stride: 4 slabs*2048
    acc.x += bf16lo(v.x); acc.y += bf16hi(v.x);
    acc.z += bf16lo(v.y); acc.w += bf16hi(v.y);
  }
  red[s][q] = acc;
  __syncthreads();

  if (t < 8) {
    float4 p = make_float4(0.f, 0.f, 0.f, 0.f);
    for (int s2 = 0; s2 < 32; ++s2) {
      float4 v = red[s2][t];
      p.x += v.x; p.y += v.y; p.z += v.z; p.w += v.w;
    }
    float4 bq4 = ((const float4*)bias)[o * 8 + t];
    p.x += bq4.x; p.y += bq4.y; p.z += bq4.z; p.w += bq4.w;
    float ns = p.x*p.x + p.y*p.y + p.z*p.z + p.w*p.w;
    ns += __shfl_xor(ns, 1);  ns += __shfl_xor(ns, 2);  ns += __shfl_xor(ns, 4);
    float sc = sqrtf(ns) / (1.0f + ns);
    ((float4*)act)[(size_t)b * 512 + o * 8 + t] =
        make_float4(p.x*sc, p.y*sc, p.z*sc, p.w*sc);
  }
}

// -------------------------------------------------------------------------
// route_kernel<PASS> (PASS = 1,2): round-9/10 structure (proven: 256-thr,
// 2 b x 8 i x all j, grid 2048 -> 8 blocks/CU), now storing part as
// PACKED bf16x2 (16 MB/pass, was 32): epilogue = 2 uint4 stores.
// -------------------------------------------------------------------------
template<int PASS>
__global__ __launch_bounds__(256) void route_kernel(
    const uint4* __restrict__ votes4, const float* __restrict__ act_in,
    unsigned* __restrict__ part, float* __restrict__ logits)
{
  __shared__ float d_lds[128];                 // [bb][o]
  __shared__ float r_lds[128];

  const int t = threadIdx.x;
  const int islab = blockIdx.x >> 3, bq = blockIdx.x & 7;
  const int i0 = islab * 8;
  const int o = t >> 2, l4 = t & 3;            // 4 threads per o, 8 j each
  const float4* __restrict__ actq = (const float4*)act_in;

  float4 av00 = actq[(size_t)(bq * 2 + 0) * 512 + 2 * t];
  float4 av01 = actq[(size_t)(bq * 2 + 0) * 512 + 2 * t + 1];
  float4 av10 = actq[(size_t)(bq * 2 + 1) * 512 + 2 * t];
  float4 av11 = actq[(size_t)(bq * 2 + 1) * 512 + 2 * t + 1];

  float4 ac00 = make_float4(0,0,0,0), ac01 = make_float4(0,0,0,0);
  float4 ac10 = make_float4(0,0,0,0), ac11 = make_float4(0,0,0,0);

  for (int il = 0; il < 8; ++il) {
    const int i = i0 + il;
    float lgv = 0.f;
    if (PASS == 2 && t < 128)                   // prefetch: hides under dist
      lgv = logits[((size_t)(bq * 2 + (t >> 6)) * I_ + i) * O_ + (t & 63)];

    const uint4* __restrict__ vo =
        votes4 + (size_t)i * 4096 + (size_t)(bq * 2) * 256 + t;
    uint4 v0 = vo[0];
    uint4 v1 = vo[256];

    // distances: full 8-j dot in-thread, then 2-step xor over the 4-group
    float c0 = bf16lo(v0.x)*av00.x + bf16hi(v0.x)*av00.y
             + bf16lo(v0.y)*av00.z + bf16hi(v0.y)*av00.w
             + bf16lo(v0.z)*av01.x + bf16hi(v0.z)*av01.y
             + bf16lo(v0.w)*av01.z + bf16hi(v0.w)*av01.w;
    c0 += __shfl_xor(c0, 1);  c0 += __shfl_xor(c0, 2);
    float c1 = bf16lo(v1.x)*av10.x + bf16hi(v1.x)*av10.y
             + bf16lo(v1.y)*av10.z + bf16hi(v1.y)*av10.w
             + bf16lo(v1.z)*av11.x + bf16hi(v1.z)*av11.y
             + bf16lo(v1.w)*av11.z + bf16hi(v1.w)*av11.w;
    c1 += __shfl_xor(c1, 1);  c1 += __shfl_xor(c1, 2);
    if (l4 == 0) d_lds[o]      = c0;
    if (l4 == 1) d_lds[64 + o] = c1;
    __syncthreads();

    // softmax over o: waves 0-1, one (bb) each; lane = o
    float ellsave = 0.f;
    if (t < 128) {
      float ell = d_lds[t];
      if (PASS == 2) ell += lgv;
      ellsave = ell;
      float m = ell;
      m = fmaxf(m, __shfl_xor(m, 32)); m = fmaxf(m, __shfl_xor(m, 16));
      m = fmaxf(m, __shfl_xor(m, 8));  m = fmaxf(m, __shfl_xor(m, 4));
      m = fmaxf(m, __shfl_xor(m, 2));  m = fmaxf(m, __shfl_xor(m, 1));
      float e = __expf(ell - m);
      float sd = e;
      sd += __shfl_xor(sd, 32); sd += __shfl_xor(sd, 16); sd += __shfl_xor(sd, 8);
      sd += __shfl_xor(sd, 4);  sd += __shfl_xor(sd, 2);  sd += __shfl_xor(sd, 1);
      r_lds[t] = e / sd;
    }
    __syncthreads();

    if (PASS == 1 && t < 128)                   // deferred: drains next il
      logits[((size_t)(bq * 2 + (t >> 6)) * I_ + i) * O_ + (t & 63)] = ellsave;

    float r0 = r_lds[o], r1 = r_lds[64 + o];
    ac00.x = fmaf(r0, bf16lo(v0.x), ac00.x); ac00.y = fmaf(r0, bf16hi(v0.x), ac00.y);
    ac00.z = fmaf(r0, bf16lo(v0.y), ac00.z); ac00.w = fmaf(r0, bf16hi(v0.y), ac00.w);
    ac01.x = fmaf(r0, bf16lo(v0.z), ac01.x); ac01.y = fmaf(r0, bf16hi(v0.z), ac01.y);
    ac01.z = fmaf(r0, bf16lo(v0.w), ac01.z); ac01.w = fmaf(r0, bf16hi(v0.w), ac01.w);
    ac10.x = fmaf(r1, bf16lo(v1.x), ac10.x); ac10.y = fmaf(r1, bf16hi(v1.x), ac10.y);
    ac10.z = fmaf(r1, bf16lo(v1.y), ac10.z); ac10.w = fmaf(r1, bf16hi(v1.y), ac10.w);
    ac11.x = fmaf(r1, bf16lo(v1.z), ac11.x); ac11.y = fmaf(r1, bf16hi(v1.z), ac11.y);
    ac11.z = fmaf(r1, bf16lo(v1.w), ac11.z); ac11.w = fmaf(r1, bf16hi(v1.w), ac11.w);
  }

  // part packed layout: [islab][16 b][1024 uint] -> uint4 row = 256/b
  uint4* __restrict__ po =
      (uint4*)part + (size_t)islab * 4096 + (size_t)(bq * 2) * 256 + t;
  po[0]   = make_uint4(pk2(ac00.x, ac00.y), pk2(ac00.z, ac00.w),
                       pk2(ac01.x, ac01.y), pk2(ac01.z, ac01.w));
  po[256] = make_uint4(pk2(ac10.x, ac10.y), pk2(ac10.z, ac10.w),
                       pk2(ac11.x, ac11.y), pk2(ac11.z, ac11.w));
}

// -------------------------------------------------------------------------
// reduce_squash_bf: preact = sum over 256 i-slabs of bf16 part; + bias;
// squash. part layout [islab][16 b][1024 uint]. One block per (b,o),
// grid 1024. Thread (s=t>>3, q=t&7) loads 8 uint2 over islab = s+32k.
// -------------------------------------------------------------------------
__global__ __launch_bounds__(256) void reduce_squash_bf(
    const unsigned* __restrict__ part, const float* __restrict__ bias,
    float* __restrict__ out)
{
  __shared__ float4 red[32][8];                // 4 KB
  const int b = blockIdx.x >> 6, o = blockIdx.x & 63;
  const int t = threadIdx.x, s = t >> 3, q = t & 7;
  const uint2* __restrict__ base =
      (const uint2*)part + (size_t)b * 512 + o * 8 + q;

  float4 acc = make_float4(0.f, 0.f, 0.f, 0.f);
  #pragma unroll
  for (int k = 0; k < 8; ++k) {
    uint2 v = base[(size_t)(s + 32 * k) * 8192];   // islab stride = 16384 uint
    acc.x += bf16lo(v.x); acc.y += bf16hi(v.x);
    acc.z += bf16lo(v.y); acc.w += bf16hi(v.y);
  }
  red[s][q] = acc;
  __syncthreads();

  if (t < 8) {
    float4 p = make_float4(0.f, 0.f, 0.f, 0.f);
    for (int s2 = 0; s2 < 32; ++s2) {
      float4 v = red[s2][t];
      p.x += v.x; p.y += v.y; p.z += v.z; p.w += v.w;
    }
    float4 bq4 = ((const float4*)bias)[o * 8 + t];
    p.x += bq4.x; p.y += bq4.y; p.z += bq4.z; p.w += bq4.w;
    float ns = p.x*p.x + p.y*p.y + p.z*p.z + p.w*p.w;
    ns += __shfl_xor(ns, 1);  ns += __shfl_xor(ns, 2);  ns += __shfl_xor(ns, 4);
    float sc = sqrtf(ns) / (1.0f + ns);
    ((float4*)out)[(size_t)b * 512 + o * 8 + t] =
        make_float4(p.x*sc, p.y*sc, p.z*sc, p.w*sc);
  }
}

// -------------------------------------------------------------------------
// FALLBACK (ws too small): W-streaming pass kernel with f32 part at
// islab*32768 + b*2048 + j, plus its f32 reducer.
// -------------------------------------------------------------------------
__global__ __launch_bounds__(256) void reduce_squash_f32(
    const float* __restrict__ part, const float* __restrict__ bias,
    float* __restrict__ out)
{
  __shared__ float4 red[32][8];
  const int b = blockIdx.x >> 6, o = blockIdx.x & 63;
  const int t = threadIdx.x, s = t >> 3, q = t & 7;
  const float4* __restrict__ base =
      (const float4*)part + (size_t)b * 512 + o * 8 + q;

  float4 acc = make_float4(0.f, 0.f, 0.f, 0.f);
  #pragma unroll
  for (int k = 0; k < 8; ++k) {
    float4 v = base[(size_t)(s + 32 * k) * 8192];
    acc.x += v.x; acc.y += v.y; acc.z += v.z; acc.w += v.w;
  }
  red[s][q] = acc;
  __syncthreads();

  if (t < 8) {
    float4 p = make_float4(0.f, 0.f, 0.f, 0.f);
    for (int s2 = 0; s2 < 32; ++s2) {
      float4 v = red[s2][t];
      p.x += v.x; p.y += v.y; p.z += v.z; p.w += v.w;
    }
    float4 bq4 = ((const float4*)bias)[o * 8 + t];
    p.x += bq4.x; p.y += bq4.y; p.z += bq4.z; p.w += bq4.w;
    float ns = p.x*p.x + p.y*p.y + p.z*p.z + p.w*p.w;
    ns += __shfl_xor(ns, 1);  ns += __shfl_xor(ns, 2);  ns += __shfl_xor(ns, 4);
    float sc = sqrtf(ns) / (1.0f + ns);
    ((float4*)out)[(size_t)b * 512 + o * 8 + t] =
        make_float4(p.x*sc, p.y*sc, p.z*sc, p.w*sc);
  }
}

template<int PASS>
__global__ __launch_bounds__(1024) void fb_pass_kernel(
    const float* __restrict__ x, const float* __restrict__ W,
    const float* __restrict__ act_in, float* __restrict__ part,
    float* __restrict__ logits)
{
  __shared__ float x_lds[8 * B_ * AIN_];
  __shared__ float d_lds[8 * O_];
  __shared__ float r_lds[8 * O_];
  const int tid = threadIdx.x, blk = blockIdx.x, i0 = blk * 8;
  for (int e = tid; e < 8 * B_ * AIN_; e += 1024) {
    int b = e >> 7, il = (e >> 4) & 7, a = e & 15;
    x_lds[il * 256 + b * 16 + a] =
        x[(size_t)b * (I_ * AIN_) + (size_t)(i0 + il) * AIN_ + a];
  }
  __syncthreads();
  const int og = tid >> 4, lg = tid & 15;
  float2 acc[16];
  #pragma unroll
  for (int b = 0; b < 16; ++b) acc[b] = make_float2(0.f, 0.f);
  const float2* __restrict__ Wq   = (const float2*)W;
  const float2* __restrict__ actq = (const float2*)act_in;
  for (int il = 0; il < 8; ++il) {
    const int i = i0 + il;
    const float2* __restrict__ Wi = Wq + (size_t)i * (AIN_ * JP_);
    const float4* __restrict__ xq = (const float4*)x_lds + il * 64;
    for (int h = 0; h < 2; ++h) {
      float2 v[8];
      #pragma unroll
      for (int bb = 0; bb < 8; ++bb) v[bb] = make_float2(0.f, 0.f);
      #pragma unroll
      for (int a4 = 0; a4 < 4; ++a4) {
        float2 w0 = Wi[(size_t)(a4 * 4 + 0) * JP_ + tid];
        float2 w1 = Wi[(size_t)(a4 * 4 + 1) * JP_ + tid];
        float2 w2 = Wi[(size_t)(a4 * 4 + 2) * JP_ + tid];
        float2 w3 = Wi[(size_t)(a4 * 4 + 3) * JP_ + tid];
        #pragma unroll
        for (int bb = 0; bb < 8; ++bb) {
          float4 xv = xq[(h * 8 + bb) * 4 + a4];
          v[bb].x = fmaf(xv.x, w0.x, v[bb].x); v[bb].y = fmaf(xv.x, w0.y, v[bb].y);
          v[bb].x = fmaf(xv.y, w1.x, v[bb].x); v[bb].y = fmaf(xv.y, w1.y, v[bb].y);
          v[bb].x = fmaf(xv.z, w2.x, v[bb].x); v[bb].y = fmaf(xv.z, w2.y, v[bb].y);
          v[bb].x = fmaf(xv.w, w3.x, v[bb].x); v[bb].y = fmaf(xv.w, w3.y, v[bb].y);
        }
      }
      if (PASS == 0) {
        #pragma unroll
        for (int bb = 0; bb < 8; ++bb) {
          acc[h * 8 + bb].x += v[bb].x; acc[h * 8 + bb].y += v[bb].y;
        }
      } else {
        #pragma unroll
        for (int bb = 0; bb < 8; ++bb) {
          const int b = h * 8 + bb;
          float2 avv = actq[(size_t)b * JP_ + tid];
          float c = v[bb].x * avv.x + v[bb].y * avv.y;
          c += __shfl_xor(c, 1); c += __shfl_xor(c, 2);
          c += __shfl_xor(c, 4); c += __shfl_xor(c, 8);
          if (lg == bb) d_lds[bb * 64 + og] = c;
        }
        __syncthreads();
        if (tid < 512) {
          const int bb2 = tid >> 6, o2 = tid & 63;
          const int b2  = h * 8 + bb2;
          float ell = d_lds[tid];
          if (PASS == 2) ell += logits[((size_t)b2 * I_ + i) * O_ + o2];
          if (PASS == 1) logits[((size_t)b2 * I_ + i) * O_ + o2] = ell;
          float m = ell;
          m = fmaxf(m, __shfl_xor(m, 32)); m = fmaxf(m, __shfl_xor(m, 16));
          m = fmaxf(m, __shfl_xor(m, 8));  m = fmaxf(m, __shfl_xor(m, 4));
          m = fmaxf(m, __shfl_xor(m, 2));  m = fmaxf(m, __shfl_xor(m, 1));
          float e = __expf(ell - m);
          float s = e;
          s += __shfl_xor(s, 32); s += __shfl_xor(s, 16); s += __shfl_xor(s, 8);
          s += __shfl_xor(s, 4);  s += __shfl_xor(s, 2);  s += __shfl_xor(s, 1);
          r_lds[tid] = e / s;
        }
        __syncthreads();
        #pragma unroll
        for (int bb = 0; bb < 8; ++bb) {
          float r = r_lds[bb * 64 + og];
          acc[h * 8 + bb].x = fmaf(r, v[bb].x, acc[h * 8 + bb].x);
          acc[h * 8 + bb].y = fmaf(r, v[bb].y, acc[h * 8 + bb].y);
        }
      }
    }
  }
  const float sc = (PASS == 0) ? (1.0f / 64.0f) : 1.0f;
  #pragma unroll
  for (int b = 0; b < 16; ++b) {
    float2* __restrict__ po = (float2*)part +
        (size_t)blk * (B_ * JP_) + (size_t)b * JP_ + tid;
    *po = make_float2(acc[b].x * sc, acc[b].y * sc);
  }
}

// -------------------------------------------------------------------------
extern "C" void kernel_launch(void* const* d_in, const int* in_sizes, int n_in,
                              void* d_out, int out_size, void* d_ws, size_t ws_size,
                              hipStream_t stream) {
  const float* x    = (const float*)d_in[0];
  const float* W    = (const float*)d_in[1];
  const float* bias = (const float*)d_in[2];
  float* out = (float*)d_out;

  float*    part   = (float*)d_ws;                        // 32 MB region (bf16 use: 16)
  float*    act    = part + (size_t)256 * (B_ * J_);      // 128 KB
  float*    logits = act + (B_ * J_);                     // 8 MB
  unsigned* votes  = (unsigned*)(logits + (size_t)B_ * I_ * O_);  // 134 MB
  const size_t need = ((size_t)256 * B_ * J_ + B_ * J_ + (size_t)B_ * I_ * O_) * 4
                    + (size_t)I_ * B_ * JP_ * 4;

  if (ws_size >= need) {
    votes_p0_kernel<<<1024, 256, 0, stream>>>(x, W, votes, (unsigned*)part);
    reduce_squash0_bf<<<1024, 256, 0, stream>>>((const unsigned*)part, bias, act);
    route_kernel<1><<<2048, 256, 0, stream>>>((const uint4*)votes, act,
                                              (unsigned*)part, logits);
    reduce_squash_bf<<<1024, 256, 0, stream>>>((const unsigned*)part, bias, act);
    route_kernel<2><<<2048, 256, 0, stream>>>((const uint4*)votes, act,
                                              (unsigned*)part, logits);
    reduce_squash_bf<<<1024, 256, 0, stream>>>((const unsigned*)part, bias, out);
  } else {
    fb_pass_kernel<0><<<256, 1024, 0, stream>>>(x, W, act, part, logits);
    reduce_squash_f32<<<1024, 256, 0, stream>>>(part, bias, act);
    fb_pass_kernel<1><<<256, 1024, 0, stream>>>(x, W, act, part, logits);
    reduce_squash_f32<<<1024, 256, 0, stream>>>(part, bias, act);
    fb_pass_kernel<2><<<256, 1024, 0, stream>>>(x, W, act, part, logits);
    reduce_squash_f32<<<1024, 256, 0, stream>>>(part, bias, out);
  }
}

// Round 12
// 164.605 us; speedup vs baseline: 1.4434x; 1.0047x over previous
//
#include <hip/hip_runtime.h>
#include <hip/hip_fp16.h>
#include <math.h>

#define B_   16
#define I_   2048
#define AIN_ 16
#define O_   64
#define J_   2048     // O*A_OUT
#define JP_  1024     // j as half2 / float2 pair-columns

// non-temporal float2 load (W is a read-once 268 MB stream; keep it out of
// L3 so the 64 MB f16 votes working set stays resident for the route passes)
__device__ __forceinline__ float2 ntload2(const float2* p) {
  union { double d; float2 f; } u;
  u.d = __builtin_nontemporal_load((const double*)p);
  return u.f;
}

// unpack a uint4 of 4 half2 (8 j) to 4 float2
__device__ __forceinline__ void unp8(const uint4 u, float2* f) {
  const __half2* h = (const __half2*)&u;
  f[0] = __half22float2(h[0]); f[1] = __half22float2(h[1]);
  f[2] = __half22float2(h[2]); f[3] = __half22float2(h[3]);
}
// pack 8 f32 (two float4) into a uint4 of half2
__device__ __forceinline__ uint4 pk8(float4 a, float4 b) {
  union { uint4 u; __half2 h[4]; } r;
  r.h[0] = __float22half2_rn(make_float2(a.x, a.y));
  r.h[1] = __float22half2_rn(make_float2(a.z, a.w));
  r.h[2] = __float22half2_rn(make_float2(b.x, b.y));
  r.h[3] = __float22half2_rn(make_float2(b.z, b.w));
  return r.u;
}

// -------------------------------------------------------------------------
// votes_p0_kernel: votes[i,b,jp] (half2) + pass-0 partials (route=1/64) ->
// part0 (half2). All vote math in packed f16 (v_pk_fma_f16): one hfma2 per
// (b, a-pair) covers both j's — half the VALU of the f32 version, and the
// votes store needs no pack instructions. Live regs ~50 (v[16]h2=16 +
// acc[16]h2=16 + cvt/addr) -> fits the 64-VGPR budget at 8 blocks/CU.
// Grid 2048 = 512 i-slabs(4 i) x 4 j-tiles(512 j); 32 waves/CU (round-8
// occupancy lesson applied to the fold). W read EXACTLY once (nt).
// f16 accuracy: 10 mantissa bits vs bf16's 7 -> vote error ~8e-4 (better).
// -------------------------------------------------------------------------
__global__ __launch_bounds__(256) void votes_p0_kernel(
    const float* __restrict__ x, const float* __restrict__ W,
    __half2* __restrict__ votes, __half2* __restrict__ part0)
{
  __shared__ __half2 x_lds[4][B_][AIN_];   // broadcast pairs (x_a,x_a); 4 KB
  const int tid = threadIdx.x;
  const int islab = blockIdx.x >> 2, jt = blockIdx.x & 3;
  const int i0 = islab * 4;

  for (int e = tid; e < 4 * B_ * AIN_; e += 256) {
    int il = e >> 8, b = (e >> 4) & 15, a = e & 15;
    float xv = x[((size_t)b * I_ + (i0 + il)) * AIN_ + a];
    x_lds[il][b][a] = __float2half2_rn(xv);
  }
  __syncthreads();

  const int jp = jt * 256 + tid;               // half2 column 0..1023
  __half2 acc[16];
  #pragma unroll
  for (int b = 0; b < 16; ++b) acc[b] = __float2half2_rn(0.f);

  for (int il = 0; il < 4; ++il) {
    const int i = i0 + il;
    const float2* __restrict__ Wi =
        (const float2*)W + (size_t)i * (AIN_ * JP_) + jp;

    __half2 v[16];
    #pragma unroll
    for (int b = 0; b < 16; ++b) v[b] = __float2half2_rn(0.f);

    #pragma unroll
    for (int a2 = 0; a2 < 8; ++a2) {
      __half2 w0 = __float22half2_rn(ntload2(Wi + (size_t)(2 * a2 + 0) * JP_));
      __half2 w1 = __float22half2_rn(ntload2(Wi + (size_t)(2 * a2 + 1) * JP_));
      #pragma unroll
      for (int b = 0; b < 16; ++b) {
        v[b] = __hfma2(x_lds[il][b][2 * a2],     w0, v[b]);
        v[b] = __hfma2(x_lds[il][b][2 * a2 + 1], w1, v[b]);
      }
    }

    __half2* __restrict__ vo = votes + (size_t)i * (B_ * JP_) + jp;
    #pragma unroll
    for (int b = 0; b < 16; ++b) {
      vo[(size_t)b * JP_] = v[b];
      acc[b] = __hadd2(acc[b], v[b]);
    }
  }

  const __half2 s64 = __float2half2_rn(1.0f / 64.0f);
  // part0 layout: [slab = islab*4 + jt][16 b][256 half2]
  __half2* __restrict__ po = part0 + (size_t)blockIdx.x * (B_ * 256) + tid;
  #pragma unroll
  for (int b = 0; b < 16; ++b)
    po[(size_t)b * 256] = __hmul2(acc[b], s64);
}

// -------------------------------------------------------------------------
// reduce_squash0_f16: act0 = squash( sum over 512 i-slabs of f16 part0
// + bias ). part0 [islab*4+jt][16 b][256 half2]. One block per (b,o),
// grid 1024. Thread (s=t>>2, q=t&3): 8 uint4 loads over islab = s + 64k.
// -------------------------------------------------------------------------
__global__ __launch_bounds__(256) void reduce_squash0_f16(
    const uint4* __restrict__ part0, const float* __restrict__ bias,
    float* __restrict__ act)
{
  __shared__ float red[64][4][8];              // 8 KB
  const int b = blockIdx.x >> 6, o = blockIdx.x & 63;
  const int t = threadIdx.x, s = t >> 2, q = t & 3;
  const uint4* __restrict__ base =
      part0 + (size_t)(o >> 4) * 1024 + b * 64 + (o & 15) * 4 + q;

  float r[8];
  #pragma unroll
  for (int e = 0; e < 8; ++e) r[e] = 0.f;
  #pragma unroll
  for (int k = 0; k < 8; ++k) {
    uint4 u = base[(size_t)(s + 64 * k) * 4096];   // islab stride = 4 slabs
    float2 f[4];
    unp8(u, f);
    r[0] += f[0].x; r[1] += f[0].y; r[2] += f[1].x; r[3] += f[1].y;
    r[4] += f[2].x; r[5] += f[2].y; r[6] += f[3].x; r[7] += f[3].y;
  }
  #pragma unroll
  for (int e = 0; e < 8; ++e) red[s][q][e] = r[e];
  __syncthreads();

  if (t < 32) {
    const int q2 = t >> 3, e = t & 7;
    float p = 0.f;
    for (int s2 = 0; s2 < 64; ++s2) p += red[s2][q2][e];
    p += bias[o * 32 + q2 * 8 + e];
    float ns = p * p;                          // squash over 32-lane a-group
    ns += __shfl_xor(ns, 1);  ns += __shfl_xor(ns, 2);
    ns += __shfl_xor(ns, 4);  ns += __shfl_xor(ns, 8);
    ns += __shfl_xor(ns, 16);
    act[(size_t)b * J_ + o * 32 + q2 * 8 + e] = p * sqrtf(ns) / (1.0f + ns);
  }
}

// -------------------------------------------------------------------------
// route_kernel<PASS> (PASS = 1,2): round-11 structure (proven: 256-thr,
// 2 b x 8 i x all j, grid 2048 -> 8 blocks/CU), f16 votes in, f16 part out.
// -------------------------------------------------------------------------
template<int PASS>
__global__ __launch_bounds__(256) void route_kernel(
    const uint4* __restrict__ votes4, const float* __restrict__ act_in,
    uint4* __restrict__ part, float* __restrict__ logits)
{
  __shared__ float d_lds[128];                 // [bb][o]
  __shared__ float r_lds[128];

  const int t = threadIdx.x;
  const int islab = blockIdx.x >> 3, bq = blockIdx.x & 7;
  const int i0 = islab * 8;
  const int o = t >> 2, l4 = t & 3;            // 4 threads per o, 8 j each
  const float4* __restrict__ actq = (const float4*)act_in;

  float4 av00 = actq[(size_t)(bq * 2 + 0) * 512 + 2 * t];
  float4 av01 = actq[(size_t)(bq * 2 + 0) * 512 + 2 * t + 1];
  float4 av10 = actq[(size_t)(bq * 2 + 1) * 512 + 2 * t];
  float4 av11 = actq[(size_t)(bq * 2 + 1) * 512 + 2 * t + 1];

  float4 ac00 = make_float4(0,0,0,0), ac01 = make_float4(0,0,0,0);
  float4 ac10 = make_float4(0,0,0,0), ac11 = make_float4(0,0,0,0);

  for (int il = 0; il < 8; ++il) {
    const int i = i0 + il;
    float lgv = 0.f;
    if (PASS == 2 && t < 128)                   // prefetch: hides under dist
      lgv = logits[((size_t)(bq * 2 + (t >> 6)) * I_ + i) * O_ + (t & 63)];

    const uint4* __restrict__ vo =
        votes4 + (size_t)i * 4096 + (size_t)(bq * 2) * 256 + t;
    float2 f0[4], f1[4];
    unp8(vo[0],   f0);
    unp8(vo[256], f1);

    // distances: full 8-j dot in-thread, then 2-step xor over the 4-group
    float c0 = f0[0].x*av00.x + f0[0].y*av00.y + f0[1].x*av00.z + f0[1].y*av00.w
             + f0[2].x*av01.x + f0[2].y*av01.y + f0[3].x*av01.z + f0[3].y*av01.w;
    c0 += __shfl_xor(c0, 1);  c0 += __shfl_xor(c0, 2);
    float c1 = f1[0].x*av10.x + f1[0].y*av10.y + f1[1].x*av10.z + f1[1].y*av10.w
             + f1[2].x*av11.x + f1[2].y*av11.y + f1[3].x*av11.z + f1[3].y*av11.w;
    c1 += __shfl_xor(c1, 1);  c1 += __shfl_xor(c1, 2);
    if (l4 == 0) d_lds[o]      = c0;
    if (l4 == 1) d_lds[64 + o] = c1;
    __syncthreads();

    // softmax over o: waves 0-1, one (bb) each; lane = o
    float ellsave = 0.f;
    if (t < 128) {
      float ell = d_lds[t];
      if (PASS == 2) ell += lgv;
      ellsave = ell;
      float m = ell;
      m = fmaxf(m, __shfl_xor(m, 32)); m = fmaxf(m, __shfl_xor(m, 16));
      m = fmaxf(m, __shfl_xor(m, 8));  m = fmaxf(m, __shfl_xor(m, 4));
      m = fmaxf(m, __shfl_xor(m, 2));  m = fmaxf(m, __shfl_xor(m, 1));
      float e = __expf(ell - m);
      float sd = e;
      sd += __shfl_xor(sd, 32); sd += __shfl_xor(sd, 16); sd += __shfl_xor(sd, 8);
      sd += __shfl_xor(sd, 4);  sd += __shfl_xor(sd, 2);  sd += __shfl_xor(sd, 1);
      r_lds[t] = e / sd;
    }
    __syncthreads();

    if (PASS == 1 && t < 128)                   // deferred: drains next il
      logits[((size_t)(bq * 2 + (t >> 6)) * I_ + i) * O_ + (t & 63)] = ellsave;

    float r0 = r_lds[o], r1 = r_lds[64 + o];
    ac00.x = fmaf(r0, f0[0].x, ac00.x); ac00.y = fmaf(r0, f0[0].y, ac00.y);
    ac00.z = fmaf(r0, f0[1].x, ac00.z); ac00.w = fmaf(r0, f0[1].y, ac00.w);
    ac01.x = fmaf(r0, f0[2].x, ac01.x); ac01.y = fmaf(r0, f0[2].y, ac01.y);
    ac01.z = fmaf(r0, f0[3].x, ac01.z); ac01.w = fmaf(r0, f0[3].y, ac01.w);
    ac10.x = fmaf(r1, f1[0].x, ac10.x); ac10.y = fmaf(r1, f1[0].y, ac10.y);
    ac10.z = fmaf(r1, f1[1].x, ac10.z); ac10.w = fmaf(r1, f1[1].y, ac10.w);
    ac11.x = fmaf(r1, f1[2].x, ac11.x); ac11.y = fmaf(r1, f1[2].y, ac11.y);
    ac11.z = fmaf(r1, f1[3].x, ac11.z); ac11.w = fmaf(r1, f1[3].y, ac11.w);
  }

  // part f16 layout: [islab][16 b][1024 half2] -> uint4 strides as before
  uint4* __restrict__ po =
      part + (size_t)islab * 4096 + (size_t)(bq * 2) * 256 + t;
  po[0]   = pk8(ac00, ac01);
  po[256] = pk8(ac10, ac11);
}

// -------------------------------------------------------------------------
// reduce_squash_f16: preact = sum over 256 i-slabs of f16 part; + bias;
// squash. part [islab][16 b][1024 half2]. One block per (b,o), grid 1024.
// Thread (s=t>>2, q=t&3): 4 uint4 loads over islab = s + 64k.
// -------------------------------------------------------------------------
__global__ __launch_bounds__(256) void reduce_squash_f16(
    const uint4* __restrict__ part, const float* __restrict__ bias,
    float* __restrict__ out)
{
  __shared__ float red[64][4][8];              // 8 KB
  const int b = blockIdx.x >> 6, o = blockIdx.x & 63;
  const int t = threadIdx.x, s = t >> 2, q = t & 3;
  const uint4* __restrict__ base =
      part + (size_t)b * 256 + o * 4 + q;

  float r[8];
  #pragma unroll
  for (int e = 0; e < 8; ++e) r[e] = 0.f;
  #pragma unroll
  for (int k = 0; k < 4; ++k) {
    uint4 u = base[(size_t)(s + 64 * k) * 4096];   // islab stride
    float2 f[4];
    unp8(u, f);
    r[0] += f[0].x; r[1] += f[0].y; r[2] += f[1].x; r[3] += f[1].y;
    r[4] += f[2].x; r[5] += f[2].y; r[6] += f[3].x; r[7] += f[3].y;
  }
  #pragma unroll
  for (int e = 0; e < 8; ++e) red[s][q][e] = r[e];
  __syncthreads();

  if (t < 32) {
    const int q2 = t >> 3, e = t & 7;
    float p = 0.f;
    for (int s2 = 0; s2 < 64; ++s2) p += red[s2][q2][e];
    p += bias[o * 32 + q2 * 8 + e];
    float ns = p * p;
    ns += __shfl_xor(ns, 1);  ns += __shfl_xor(ns, 2);
    ns += __shfl_xor(ns, 4);  ns += __shfl_xor(ns, 8);
    ns += __shfl_xor(ns, 16);
    out[(size_t)b * J_ + o * 32 + q2 * 8 + e] = p * sqrtf(ns) / (1.0f + ns);
  }
}

// -------------------------------------------------------------------------
// FALLBACK (ws too small): W-streaming pass kernel with f32 part at
// islab*32768 + b*2048 + j, plus its f32 reducer.
// -------------------------------------------------------------------------
__global__ __launch_bounds__(256) void reduce_squash_f32(
    const float* __restrict__ part, const float* __restrict__ bias,
    float* __restrict__ out)
{
  __shared__ float4 red[32][8];
  const int b = blockIdx.x >> 6, o = blockIdx.x & 63;
  const int t = threadIdx.x, s = t >> 3, q = t & 7;
  const float4* __restrict__ base =
      (const float4*)part + (size_t)b * 512 + o * 8 + q;

  float4 acc = make_float4(0.f, 0.f, 0.f, 0.f);
  #pragma unroll
  for (int k = 0; k < 8; ++k) {
    float4 v = base[(size_t)(s + 32 * k) * 8192];
    acc.x += v.x; acc.y += v.y; acc.z += v.z; acc.w += v.w;
  }
  red[s][q] = acc;
  __syncthreads();

  if (t < 8) {
    float4 p = make_float4(0.f, 0.f, 0.f, 0.f);
    for (int s2 = 0; s2 < 32; ++s2) {
      float4 v = red[s2][t];
      p.x += v.x; p.y += v.y; p.z += v.z; p.w += v.w;
    }
    float4 bq4 = ((const float4*)bias)[o * 8 + t];
    p.x += bq4.x; p.y += bq4.y; p.z += bq4.z; p.w += bq4.w;
    float ns = p.x*p.x + p.y*p.y + p.z*p.z + p.w*p.w;
    ns += __shfl_xor(ns, 1);  ns += __shfl_xor(ns, 2);  ns += __shfl_xor(ns, 4);
    float sc = sqrtf(ns) / (1.0f + ns);
    ((float4*)out)[(size_t)b * 512 + o * 8 + t] =
        make_float4(p.x*sc, p.y*sc, p.z*sc, p.w*sc);
  }
}

template<int PASS>
__global__ __launch_bounds__(1024) void fb_pass_kernel(
    const float* __restrict__ x, const float* __restrict__ W,
    const float* __restrict__ act_in, float* __restrict__ part,
    float* __restrict__ logits)
{
  __shared__ float x_lds[8 * B_ * AIN_];
  __shared__ float d_lds[8 * O_];
  __shared__ float r_lds[8 * O_];
  const int tid = threadIdx.x, blk = blockIdx.x, i0 = blk * 8;
  for (int e = tid; e < 8 * B_ * AIN_; e += 1024) {
    int b = e >> 7, il = (e >> 4) & 7, a = e & 15;
    x_lds[il * 256 + b * 16 + a] =
        x[(size_t)b * (I_ * AIN_) + (size_t)(i0 + il) * AIN_ + a];
  }
  __syncthreads();
  const int og = tid >> 4, lg = tid & 15;
  float2 acc[16];
  #pragma unroll
  for (int b = 0; b < 16; ++b) acc[b] = make_float2(0.f, 0.f);
  const float2* __restrict__ Wq   = (const float2*)W;
  const float2* __restrict__ actq = (const float2*)act_in;
  for (int il = 0; il < 8; ++il) {
    const int i = i0 + il;
    const float2* __restrict__ Wi = Wq + (size_t)i * (AIN_ * JP_);
    const float4* __restrict__ xq = (const float4*)x_lds + il * 64;
    for (int h = 0; h < 2; ++h) {
      float2 v[8];
      #pragma unroll
      for (int bb = 0; bb < 8; ++bb) v[bb] = make_float2(0.f, 0.f);
      #pragma unroll
      for (int a4 = 0; a4 < 4; ++a4) {
        float2 w0 = Wi[(size_t)(a4 * 4 + 0) * JP_ + tid];
        float2 w1 = Wi[(size_t)(a4 * 4 + 1) * JP_ + tid];
        float2 w2 = Wi[(size_t)(a4 * 4 + 2) * JP_ + tid];
        float2 w3 = Wi[(size_t)(a4 * 4 + 3) * JP_ + tid];
        #pragma unroll
        for (int bb = 0; bb < 8; ++bb) {
          float4 xv = xq[(h * 8 + bb) * 4 + a4];
          v[bb].x = fmaf(xv.x, w0.x, v[bb].x); v[bb].y = fmaf(xv.x, w0.y, v[bb].y);
          v[bb].x = fmaf(xv.y, w1.x, v[bb].x); v[bb].y = fmaf(xv.y, w1.y, v[bb].y);
          v[bb].x = fmaf(xv.z, w2.x, v[bb].x); v[bb].y = fmaf(xv.z, w2.y, v[bb].y);
          v[bb].x = fmaf(xv.w, w3.x, v[bb].x); v[bb].y = fmaf(xv.w, w3.y, v[bb].y);
        }
      }
      if (PASS == 0) {
        #pragma unroll
        for (int bb = 0; bb < 8; ++bb) {
          acc[h * 8 + bb].x += v[bb].x; acc[h * 8 + bb].y += v[bb].y;
        }
      } else {
        #pragma unroll
        for (int bb = 0; bb < 8; ++bb) {
          const int b = h * 8 + bb;
          float2 avv = actq[(size_t)b * JP_ + tid];
          float c = v[bb].x * avv.x + v[bb].y * avv.y;
          c += __shfl_xor(c, 1); c += __shfl_xor(c, 2);
          c += __shfl_xor(c, 4); c += __shfl_xor(c, 8);
          if (lg == bb) d_lds[bb * 64 + og] = c;
        }
        __syncthreads();
        if (tid < 512) {
          const int bb2 = tid >> 6, o2 = tid & 63;
          const int b2  = h * 8 + bb2;
          float ell = d_lds[tid];
          if (PASS == 2) ell += logits[((size_t)b2 * I_ + i) * O_ + o2];
          if (PASS == 1) logits[((size_t)b2 * I_ + i) * O_ + o2] = ell;
          float m = ell;
          m = fmaxf(m, __shfl_xor(m, 32)); m = fmaxf(m, __shfl_xor(m, 16));
          m = fmaxf(m, __shfl_xor(m, 8));  m = fmaxf(m, __shfl_xor(m, 4));
          m = fmaxf(m, __shfl_xor(m, 2));  m = fmaxf(m, __shfl_xor(m, 1));
          float e = __expf(ell - m);
          float s = e;
          s += __shfl_xor(s, 32); s += __shfl_xor(s, 16); s += __shfl_xor(s, 8);
          s += __shfl_xor(s, 4);  s += __shfl_xor(s, 2);  s += __shfl_xor(s, 1);
          r_lds[tid] = e / s;
        }
        __syncthreads();
        #pragma unroll
        for (int bb = 0; bb < 8; ++bb) {
          float r = r_lds[bb * 64 + og];
          acc[h * 8 + bb].x = fmaf(r, v[bb].x, acc[h * 8 + bb].x);
          acc[h * 8 + bb].y = fmaf(r, v[bb].y, acc[h * 8 + bb].y);
        }
      }
    }
  }
  const float sc = (PASS == 0) ? (1.0f / 64.0f) : 1.0f;
  #pragma unroll
  for (int b = 0; b < 16; ++b) {
    float2* __restrict__ po = (float2*)part +
        (size_t)blk * (B_ * JP_) + (size_t)b * JP_ + tid;
    *po = make_float2(acc[b].x * sc, acc[b].y * sc);
  }
}

// -------------------------------------------------------------------------
extern "C" void kernel_launch(void* const* d_in, const int* in_sizes, int n_in,
                              void* d_out, int out_size, void* d_ws, size_t ws_size,
                              hipStream_t stream) {
  const float* x    = (const float*)d_in[0];
  const float* W    = (const float*)d_in[1];
  const float* bias = (const float*)d_in[2];
  float* out = (float*)d_out;

  float*   part   = (float*)d_ws;                        // 32 MiB region
  float*   act    = part + (size_t)256 * (B_ * J_);      // 128 KB
  float*   logits = act + (B_ * J_);                     // 8 MB
  __half2* votes  = (__half2*)(logits + (size_t)B_ * I_ * O_);  // 64 MB f16
  const size_t need = ((size_t)256 * B_ * J_ + B_ * J_ + (size_t)B_ * I_ * O_) * 4
                    + (size_t)I_ * B_ * JP_ * 4;

  if (ws_size >= need) {
    votes_p0_kernel<<<2048, 256, 0, stream>>>(x, W, votes, (__half2*)part);
    reduce_squash0_f16<<<1024, 256, 0, stream>>>((const uint4*)part, bias, act);
    route_kernel<1><<<2048, 256, 0, stream>>>((const uint4*)votes, act,
                                              (uint4*)part, logits);
    reduce_squash_f16<<<1024, 256, 0, stream>>>((const uint4*)part, bias, act);
    route_kernel<2><<<2048, 256, 0, stream>>>((const uint4*)votes, act,
                                              (uint4*)part, logits);
    reduce_squash_f16<<<1024, 256, 0, stream>>>((const uint4*)part, bias, out);
  } else {
    fb_pass_kernel<0><<<256, 1024, 0, stream>>>(x, W, act, part, logits);
    reduce_squash_f32<<<1024, 256, 0, stream>>>(part, bias, act);
    fb_pass_kernel<1><<<256, 1024, 0, stream>>>(x, W, act, part, logits);
    reduce_squash_f32<<<1024, 256, 0, stream>>>(part, bias, act);
    fb_pass_kernel<2><<<256, 1024, 0, stream>>>(x, W, act, part, logits);
    reduce_squash_f32<<<1024, 256, 0, stream>>>(part, bias, out);
  }
}